// Round 4
// baseline (355.840 us; speedup 1.0000x reference)
//
#include <hip/hip_runtime.h>
#include <hip/hip_bf16.h>
#include <cstddef>

#define BATCH   16
#define SEQ     1024
#define D_MODEL 128
#define D_STATE 16
#define D_CONVK 4
#define D_INNER 256
#define N_LAYERS 2
#define NTOK    (BATCH*SEQ)   /* 16384 */
#define LN_EPS  1e-5f
#define CL      32            /* scan chunk length */
#define NC      32            /* chunks per sequence */

typedef __attribute__((ext_vector_type(8))) short bf16x8;
typedef __attribute__((ext_vector_type(4))) float f32x4;

__device__ __forceinline__ float siluf(float v){ return v / (1.f + __expf(-v)); }
__device__ __forceinline__ float softplusf(float x){ return x > 20.f ? x : log1pf(__expf(x)); }
__device__ __forceinline__ short f2b(float f){
  __hip_bfloat16 h = __float2bfloat16(f);
  return *reinterpret_cast<short*>(&h);
}
__device__ __forceinline__ float b2f(short s){
  union { unsigned u; float f; } v; v.u = ((unsigned)(unsigned short)s) << 16; return v.f;
}

// ---------------- fused weight transpose+convert (all weights, one kernel) ----------------
struct CT {
  const float* src[9];
  __hip_bfloat16* dst[9];
  int lg2K[9], ld[9], coff[9];
  int bstart[9];
};
__global__ __launch_bounds__(256) void convT_all(CT c){
  int bid = blockIdx.x, r = 0;
  #pragma unroll
  for (int i=1;i<9;i++) r = (bid >= c.bstart[i]) ? i : r;
  int idx = (bid - c.bstart[r])*256 + threadIdx.x;
  int lg = c.lg2K[r];
  int k = idx & ((1<<lg)-1), n = idx >> lg;
  c.dst[r][idx] = __float2bfloat16(c.src[r][(size_t)k*c.ld[r] + c.coff[r] + n]);
}

// ---------------- LayerNorm: wave per row, 4 rows/block ----------------
template<bool OUT_BF16>
__global__ __launch_bounds__(256) void ln_kernel(
    const float* __restrict__ in, void* __restrict__ outp,
    const float* __restrict__ w, const float* __restrict__ b){
  int row = blockIdx.x*4 + (threadIdx.x >> 6);
  int t = threadIdx.x & 63;
  const float* r = in + (size_t)row*D_MODEL;
  float a0 = r[t], a1 = r[t+64];
  float s = a0 + a1;
  #pragma unroll
  for (int off=32; off; off>>=1) s += __shfl_xor(s, off);
  float mu = s * (1.f/128.f);
  float d0 = a0-mu, d1 = a1-mu;
  float v = d0*d0 + d1*d1;
  #pragma unroll
  for (int off=32; off; off>>=1) v += __shfl_xor(v, off);
  float rs = rsqrtf(v*(1.f/128.f) + LN_EPS);
  float o0 = d0*rs*w[t] + b[t];
  float o1 = d1*rs*w[t+64] + b[t+64];
  if (OUT_BF16){
    __hip_bfloat16* out = (__hip_bfloat16*)outp;
    out[(size_t)row*D_MODEL + t]    = __float2bfloat16(o0);
    out[(size_t)row*D_MODEL + t+64] = __float2bfloat16(o1);
  } else {
    float* out = (float*)outp;
    out[(size_t)row*D_MODEL + t]    = o0;
    out[(size_t)row*D_MODEL + t+64] = o1;
  }
}

// ---------------- bf16 MFMA GEMM ----------------
// A: row-major [M][lda] (bf16, or fp32 staged-converted). Bt: bf16 [N][K].
// BM=BN=64, BK=32, 256 threads = 4 waves (2x2 of 32x32).
#define EPI_F32      0   /* C fp32 store (+bias opt) */
#define EPI_F32_ACC  1   /* C fp32 +=                */
#define EPI_BF16_SP  2   /* C bf16 softplus(+bias)   */
#define EPI_SPLITZ   3   /* cols<256 -> C bf16; cols>=256 -> C2 bf16 silu */

template<bool A_FP32, bool BIAS, int EPI>
__global__ __launch_bounds__(256) void mfma_gemm(
    const void* __restrict__ Aptr, const __hip_bfloat16* __restrict__ Bt,
    const float* __restrict__ bias, void* __restrict__ Cptr, void* __restrict__ C2ptr,
    int lda, int K, int Nvalid, int ldc){
  __shared__ __align__(16) short As[64][40];
  __shared__ __align__(16) short Bs[64][40];
  int tid = threadIdx.x;
  int row0 = blockIdx.y * 64, col0 = blockIdx.x * 64;
  int r = tid >> 2, seg = tid & 3;
  int lane = tid & 63, w = tid >> 6;
  int wr = (w >> 1) * 32, wc = (w & 1) * 32;
  int fr = lane & 15, fq = lane >> 4;
  f32x4 acc00 = {}, acc01 = {}, acc10 = {}, acc11 = {};
  for (int k0 = 0; k0 < K; k0 += 32){
    if (A_FP32){
      const float* Af = (const float*)Aptr + (size_t)(row0+r)*lda + k0 + seg*8;
      float4 a0 = *(const float4*)Af;
      float4 a1 = *(const float4*)(Af+4);
      bf16x8 v;
      v[0]=f2b(a0.x); v[1]=f2b(a0.y); v[2]=f2b(a0.z); v[3]=f2b(a0.w);
      v[4]=f2b(a1.x); v[5]=f2b(a1.y); v[6]=f2b(a1.z); v[7]=f2b(a1.w);
      *(bf16x8*)&As[r][seg*8] = v;
    } else {
      const __hip_bfloat16* Ab = (const __hip_bfloat16*)Aptr + (size_t)(row0+r)*lda + k0 + seg*8;
      *(bf16x8*)&As[r][seg*8] = *(const bf16x8*)Ab;
    }
    bf16x8 bv = {};
    if (col0 + r < Nvalid)
      bv = *(const bf16x8*)(Bt + (size_t)(col0+r)*K + k0 + seg*8);
    *(bf16x8*)&Bs[r][seg*8] = bv;
    __syncthreads();
    bf16x8 a0 = *(bf16x8*)&As[wr + fr][fq*8];
    bf16x8 a1 = *(bf16x8*)&As[wr + 16 + fr][fq*8];
    bf16x8 b0 = *(bf16x8*)&Bs[wc + fr][fq*8];
    bf16x8 b1 = *(bf16x8*)&Bs[wc + 16 + fr][fq*8];
    acc00 = __builtin_amdgcn_mfma_f32_16x16x32_bf16(a0, b0, acc00, 0, 0, 0);
    acc01 = __builtin_amdgcn_mfma_f32_16x16x32_bf16(a0, b1, acc01, 0, 0, 0);
    acc10 = __builtin_amdgcn_mfma_f32_16x16x32_bf16(a1, b0, acc10, 0, 0, 0);
    acc11 = __builtin_amdgcn_mfma_f32_16x16x32_bf16(a1, b1, acc11, 0, 0, 0);
    __syncthreads();
  }
  f32x4 accs[2][2] = {{acc00, acc01},{acc10, acc11}};
  #pragma unroll
  for (int mr=0; mr<2; mr++){
    #pragma unroll
    for (int nc2=0; nc2<2; nc2++){
      int gcol = col0 + wc + nc2*16 + fr;
      if (gcol < Nvalid){
        float bval = BIAS ? bias[gcol] : 0.f;
        #pragma unroll
        for (int q=0; q<4; q++){
          int grow = row0 + wr + mr*16 + fq*4 + q;
          float v = accs[mr][nc2][q] + bval;
          if (EPI == EPI_F32){
            ((float*)Cptr)[(size_t)grow*ldc + gcol] = v;
          } else if (EPI == EPI_F32_ACC){
            float* p = (float*)Cptr + (size_t)grow*ldc + gcol; *p += v;
          } else if (EPI == EPI_BF16_SP){
            ((__hip_bfloat16*)Cptr)[(size_t)grow*ldc + gcol] = __float2bfloat16(softplusf(v));
          } else {
            if (gcol < D_INNER)
              ((__hip_bfloat16*)Cptr)[(size_t)grow*D_INNER + gcol] = __float2bfloat16(v);
            else
              ((__hip_bfloat16*)C2ptr)[(size_t)grow*D_INNER + gcol - D_INNER] = __float2bfloat16(siluf(v));
          }
        }
      }
    }
  }
}

// ---------------- Causal depthwise conv1d(K=4) + bias + silu, bf16 in/out ----------------
__global__ __launch_bounds__(256) void conv_silu_kernel(
    const __hip_bfloat16* __restrict__ xraw, const float* __restrict__ cw,
    const float* __restrict__ cb, __hip_bfloat16* __restrict__ xi){
  int g = blockIdx.x*256 + threadIdx.x;   // NTOK*32 threads, 8 channels each
  int t = g >> 5;
  int d0 = (g & 31) << 3;
  int l = t & (SEQ-1);
  float acc[8];
  #pragma unroll
  for (int j=0;j<8;j++) acc[j] = cb[d0+j];
  #pragma unroll
  for (int k=0;k<D_CONVK;k++){
    int ls = l + k - (D_CONVK-1);
    if (ls >= 0){
      bf16x8 v = *(const bf16x8*)(xraw + (size_t)(t - (D_CONVK-1) + k)*D_INNER + d0);
      #pragma unroll
      for (int j=0;j<8;j++)
        acc[j] = fmaf(b2f(v[j]), cw[(d0+j)*D_CONVK + k], acc[j]);
    }
  }
  bf16x8 o;
  #pragma unroll
  for (int j=0;j<8;j++) o[j] = f2b(siluf(acc[j]));
  *(bf16x8*)(xi + (size_t)t*D_INNER + d0) = o;
}

// ---------------- Chunked selective scan (bf16 activations, fp32 state) ----------------
__global__ __launch_bounds__(256) void scan_p1(
    const __hip_bfloat16* __restrict__ delta, const __hip_bfloat16* __restrict__ xi,
    const float* __restrict__ Bm, const float* __restrict__ A_log,
    float* __restrict__ cs, float* __restrict__ sumdlt){
  int bc = blockIdx.x;               // b*NC + c
  int c = bc & (NC-1);
  int b = bc >> 5;
  int d = threadIdx.x;
  float Aa[D_STATE];
  #pragma unroll
  for (int n=0;n<D_STATE;n++) Aa[n] = -__expf(A_log[d*D_STATE + n]);
  float s[D_STATE] = {};
  float sd = 0.f;
  size_t t0 = (size_t)b*SEQ + (size_t)c*CL;
  #pragma unroll 4
  for (int l=0; l<CL; l++){
    size_t t = t0 + l;
    float dlt = __bfloat162float(delta[t*D_INNER + d]);
    float xv  = __bfloat162float(xi[t*D_INNER + d]);
    const float4* bmr = (const float4*)(Bm + t*D_STATE);
    float4 q0=bmr[0], q1=bmr[1], q2=bmr[2], q3=bmr[3];
    float bm[D_STATE] = {q0.x,q0.y,q0.z,q0.w, q1.x,q1.y,q1.z,q1.w,
                         q2.x,q2.y,q2.z,q2.w, q3.x,q3.y,q3.z,q3.w};
    sd += dlt;
    float dx = dlt * xv;
    #pragma unroll
    for (int n=0;n<D_STATE;n++)
      s[n] = fmaf(__expf(dlt * Aa[n]), s[n], dx * bm[n]);
  }
  float4* out = (float4*)(cs + ((size_t)bc*D_INNER + d)*D_STATE);
  out[0] = make_float4(s[0],s[1],s[2],s[3]);
  out[1] = make_float4(s[4],s[5],s[6],s[7]);
  out[2] = make_float4(s[8],s[9],s[10],s[11]);
  out[3] = make_float4(s[12],s[13],s[14],s[15]);
  sumdlt[(size_t)bc*D_INNER + d] = sd;
}

__global__ __launch_bounds__(256) void scan_p2(
    const float* __restrict__ A_log, float* __restrict__ cs,
    const float* __restrict__ sumdlt){
  int b = blockIdx.x;
  int d = threadIdx.x;
  float Aa[D_STATE];
  #pragma unroll
  for (int n=0;n<D_STATE;n++) Aa[n] = -__expf(A_log[d*D_STATE + n]);
  float s[D_STATE] = {};
  #pragma unroll
  for (int c=0;c<NC;c++){
    size_t base = ((size_t)(b*NC + c)*D_INNER + d)*D_STATE;
    float4* p = (float4*)(cs + base);
    float4 e0=p[0], e1=p[1], e2=p[2], e3=p[3];
    float se[D_STATE] = {e0.x,e0.y,e0.z,e0.w, e1.x,e1.y,e1.z,e1.w,
                         e2.x,e2.y,e2.z,e2.w, e3.x,e3.y,e3.z,e3.w};
    float sd = sumdlt[(size_t)(b*NC + c)*D_INNER + d];
    float sin_[D_STATE];
    #pragma unroll
    for (int n=0;n<D_STATE;n++){
      sin_[n] = s[n];
      s[n] = fmaf(__expf(Aa[n]*sd), s[n], se[n]);
    }
    p[0] = make_float4(sin_[0],sin_[1],sin_[2],sin_[3]);
    p[1] = make_float4(sin_[4],sin_[5],sin_[6],sin_[7]);
    p[2] = make_float4(sin_[8],sin_[9],sin_[10],sin_[11]);
    p[3] = make_float4(sin_[12],sin_[13],sin_[14],sin_[15]);
  }
}

__global__ __launch_bounds__(256) void scan_p3(
    const __hip_bfloat16* __restrict__ delta, const __hip_bfloat16* __restrict__ xi,
    const float* __restrict__ Bm, const __hip_bfloat16* __restrict__ zs,
    const float* __restrict__ A_log, const float* __restrict__ Dp,
    const float* __restrict__ cs, __hip_bfloat16* __restrict__ ybf){
  int bc = blockIdx.x;
  int c = bc & (NC-1);
  int b = bc >> 5;
  int d = threadIdx.x;
  float Aa[D_STATE];
  #pragma unroll
  for (int n=0;n<D_STATE;n++) Aa[n] = -__expf(A_log[d*D_STATE + n]);
  float Dv = Dp[d];
  const float4* sp = (const float4*)(cs + ((size_t)bc*D_INNER + d)*D_STATE);
  float4 s0=sp[0], s1=sp[1], s2=sp[2], s3=sp[3];
  float s[D_STATE] = {s0.x,s0.y,s0.z,s0.w, s1.x,s1.y,s1.z,s1.w,
                      s2.x,s2.y,s2.z,s2.w, s3.x,s3.y,s3.z,s3.w};
  size_t t0 = (size_t)b*SEQ + (size_t)c*CL;
  #pragma unroll 4
  for (int l=0; l<CL; l++){
    size_t t = t0 + l;
    float dlt = __bfloat162float(delta[t*D_INNER + d]);
    float xv  = __bfloat162float(xi[t*D_INNER + d]);
    float zv  = __bfloat162float(zs[t*D_INNER + d]);
    const float4* bmr = (const float4*)(Bm + t*D_STATE);
    float4 q0=bmr[0], q1=bmr[1], q2=bmr[2], q3=bmr[3];
    float bm[D_STATE] = {q0.x,q0.y,q0.z,q0.w, q1.x,q1.y,q1.z,q1.w,
                         q2.x,q2.y,q2.z,q2.w, q3.x,q3.y,q3.z,q3.w};
    float dx = dlt * xv;
    float y = 0.f;
    #pragma unroll
    for (int n=0;n<D_STATE;n++){
      s[n] = fmaf(__expf(dlt * Aa[n]), s[n], dx * bm[n]);
      y = fmaf(s[n], bm[n], y);
    }
    ybf[t*D_INNER + d] = __float2bfloat16((y + Dv*xv) * zv);
  }
}

extern "C" void kernel_launch(void* const* d_in, const int* in_sizes, int n_in,
                              void* d_out, int out_size, void* d_ws, size_t ws_size,
                              hipStream_t stream){
  const float* x      = (const float*)d_in[0];
  const float* inp_w  = (const float*)d_in[1];
  const float* inp_b  = (const float*)d_in[2];
  const float* ln_w   = (const float*)d_in[3];
  const float* ln_b   = (const float*)d_in[4];
  const float* in_w   = (const float*)d_in[5];
  const float* conv_w = (const float*)d_in[6];
  const float* conv_b = (const float*)d_in[7];
  const float* xproj_w= (const float*)d_in[8];
  const float* dt_w   = (const float*)d_in[9];
  const float* dt_b   = (const float*)d_in[10];
  const float* A_log  = (const float*)d_in[11];
  const float* Dp     = (const float*)d_in[12];
  const float* out_w  = (const float*)d_in[13];
  const float* fn_w   = (const float*)d_in[14];
  const float* fn_b   = (const float*)d_in[15];

  float* h = (float*)d_out;                          // (NTOK,128) residual stream

  __hip_bfloat16* xraw = (__hip_bfloat16*)d_ws;       // NTOK*256
  __hip_bfloat16* zs   = xraw + (size_t)NTOK*256;     // NTOK*256 (silu(z))
  __hip_bfloat16* xi   = zs   + (size_t)NTOK*256;     // NTOK*256
  __hip_bfloat16* dlt  = xi   + (size_t)NTOK*256;     // NTOK*256
  __hip_bfloat16* ybf  = dlt  + (size_t)NTOK*256;     // NTOK*256
  __hip_bfloat16* hnbf = ybf  + (size_t)NTOK*256;     // NTOK*128
  float* Bm    = (float*)(hnbf + (size_t)NTOK*128);   // NTOK*16
  float* cs    = Bm + (size_t)NTOK*16;                // 16*NC*256*16
  float* sumdlt= cs + (size_t)16*NC*D_INNER*D_STATE;  // 16*NC*256
  __hip_bfloat16* w_inpT = (__hip_bfloat16*)(sumdlt + (size_t)16*NC*D_INNER);
  __hip_bfloat16* w_inT  = w_inpT + 128*64;
  __hip_bfloat16* w_dtT  = w_inT  + 2*512*128;
  __hip_bfloat16* w_xpT  = w_dtT  + 2*256*256;
  __hip_bfloat16* w_outT = w_xpT  + 2*16*256;

  // ---- one fused weight convert+transpose dispatch ----
  CT ct;
  ct.src[0]=inp_w;            ct.dst[0]=w_inpT;          ct.lg2K[0]=6; ct.ld[0]=128; ct.coff[0]=0;
  ct.src[1]=in_w;             ct.dst[1]=w_inT;           ct.lg2K[1]=7; ct.ld[1]=512; ct.coff[1]=0;
  ct.src[2]=in_w+65536;       ct.dst[2]=w_inT+65536;     ct.lg2K[2]=7; ct.ld[2]=512; ct.coff[2]=0;
  ct.src[3]=dt_w;             ct.dst[3]=w_dtT;           ct.lg2K[3]=8; ct.ld[3]=256; ct.coff[3]=0;
  ct.src[4]=dt_w+65536;       ct.dst[4]=w_dtT+65536;     ct.lg2K[4]=8; ct.ld[4]=256; ct.coff[4]=0;
  ct.src[5]=xproj_w;          ct.dst[5]=w_xpT;           ct.lg2K[5]=8; ct.ld[5]=32;  ct.coff[5]=16;
  ct.src[6]=xproj_w+8192;     ct.dst[6]=w_xpT+4096;      ct.lg2K[6]=8; ct.ld[6]=32;  ct.coff[6]=16;
  ct.src[7]=out_w;            ct.dst[7]=w_outT;          ct.lg2K[7]=8; ct.ld[7]=128; ct.coff[7]=0;
  ct.src[8]=out_w+32768;      ct.dst[8]=w_outT+32768;    ct.lg2K[8]=8; ct.ld[8]=128; ct.coff[8]=0;
  int bs[9] = {0,32,288,544,800,1056,1072,1088,1216};
  for (int i=0;i<9;i++) ct.bstart[i]=bs[i];
  convT_all<<<1344, 256, 0, stream>>>(ct);

  // h = x @ inp_w + inp_b   (A fp32 staged, K=64, N=128)
  mfma_gemm<true,true,EPI_F32><<<dim3(2, NTOK/64), 256, 0, stream>>>(
      x, w_inpT, inp_b, h, nullptr, 64, 64, 128, 128);

  for (int i=0;i<N_LAYERS;i++){
    ln_kernel<true><<<NTOK/4, 256, 0, stream>>>(h, hnbf, ln_w + i*D_MODEL, ln_b + i*D_MODEL);
    // xraw | zs = hn @ in_w  (K=128, N=512, split epilogue with fused silu on z)
    mfma_gemm<false,false,EPI_SPLITZ><<<dim3(8, NTOK/64), 256, 0, stream>>>(
        hnbf, w_inT + (size_t)i*512*128, nullptr, xraw, zs, 128, 128, 512, 0);
    conv_silu_kernel<<<NTOK/8, 256, 0, stream>>>(
        xraw, conv_w + i*D_INNER*D_CONVK, conv_b + i*D_INNER, xi);
    // Bm = xi @ xproj_w[:,16:32]  (K=256, N=16)
    mfma_gemm<false,false,EPI_F32><<<dim3(1, NTOK/64), 256, 0, stream>>>(
        xi, w_xpT + (size_t)i*16*256, nullptr, Bm, nullptr, 256, 256, 16, 16);
    // delta = softplus(xi @ dt_w + dt_b)  (K=256, N=256, bf16 out)
    mfma_gemm<false,true,EPI_BF16_SP><<<dim3(4, NTOK/64), 256, 0, stream>>>(
        xi, w_dtT + (size_t)i*256*256, dt_b + i*D_INNER, dlt, nullptr, 256, 256, 256, 256);
    // chunked scan
    const float* Al = A_log + (size_t)i*D_INNER*D_STATE;
    scan_p1<<<BATCH*NC, 256, 0, stream>>>(dlt, xi, Bm, Al, cs, sumdlt);
    scan_p2<<<BATCH, 256, 0, stream>>>(Al, cs, sumdlt);
    scan_p3<<<BATCH*NC, 256, 0, stream>>>(dlt, xi, Bm, zs, Al, Dp + i*D_INNER, cs, ybf);
    // h += y @ out_w  (K=256, N=128)
    mfma_gemm<false,false,EPI_F32_ACC><<<dim3(2, NTOK/64), 256, 0, stream>>>(
        ybf, w_outT + (size_t)i*128*256, nullptr, h, nullptr, 256, 256, 128, 128);
  }
  ln_kernel<false><<<NTOK/4, 256, 0, stream>>>(h, h, fn_w, fn_b);
}

// Round 5
// 326.917 us; speedup vs baseline: 1.0885x; 1.0885x over previous
//
#include <hip/hip_runtime.h>
#include <hip/hip_bf16.h>
#include <cstddef>

#define BATCH   16
#define SEQ     1024
#define D_MODEL 128
#define D_STATE 16
#define D_CONVK 4
#define D_INNER 256
#define N_LAYERS 2
#define NTOK    (BATCH*SEQ)   /* 16384 */
#define LN_EPS  1e-5f
#define CL      32            /* scan chunk length */
#define NC      32            /* chunks per sequence */

typedef __attribute__((ext_vector_type(8))) short bf16x8;
typedef __attribute__((ext_vector_type(4))) float f32x4;

__device__ __forceinline__ float siluf(float v){ return v / (1.f + __expf(-v)); }
__device__ __forceinline__ float softplusf(float x){ return x > 20.f ? x : log1pf(__expf(x)); }
__device__ __forceinline__ short f2b(float f){
  __hip_bfloat16 h = __float2bfloat16(f);
  return *reinterpret_cast<short*>(&h);
}
__device__ __forceinline__ float b2f(short s){
  union { unsigned u; float f; } v; v.u = ((unsigned)(unsigned short)s) << 16; return v.f;
}

// ---------------- fused weight transpose+convert (all weights, one kernel) ----------------
struct CT {
  const float* src[9];
  __hip_bfloat16* dst[9];
  int lg2K[9], ld[9], coff[9];
  int bstart[9];
};
__global__ __launch_bounds__(256) void convT_all(CT c){
  int bid = blockIdx.x, r = 0;
  #pragma unroll
  for (int i=1;i<9;i++) r = (bid >= c.bstart[i]) ? i : r;
  int idx = (bid - c.bstart[r])*256 + threadIdx.x;
  int lg = c.lg2K[r];
  int k = idx & ((1<<lg)-1), n = idx >> lg;
  c.dst[r][idx] = __float2bfloat16(c.src[r][(size_t)k*c.ld[r] + c.coff[r] + n]);
}

// ---------------- fused input-proj GEMM + LN0 ----------------
// block: 64 tokens x full 128 cols, K=64. Writes h fp32 raw + hnbf = LN(h).
__global__ __launch_bounds__(256) void inp_ln_kernel(
    const float* __restrict__ x, const __hip_bfloat16* __restrict__ wb,
    const float* __restrict__ bias, float* __restrict__ h,
    __hip_bfloat16* __restrict__ hnbf,
    const float* __restrict__ lnw, const float* __restrict__ lnb){
  __shared__ __align__(16) short As[64][72];
  __shared__ __align__(16) short Bs[128][72];
  __shared__ float hls[64][133];
  __shared__ float psum[4][64], psumsq[4][64], mu_s[64], rs_s[64];
  int tid = threadIdx.x;
  int row0 = blockIdx.x*64;
  int r = tid>>2, seg = tid&3;
  #pragma unroll
  for (int k0=0;k0<64;k0+=32){
    const float* Af = x + (size_t)(row0+r)*64 + k0 + seg*8;
    float4 a0 = *(const float4*)Af;
    float4 a1 = *(const float4*)(Af+4);
    bf16x8 v;
    v[0]=f2b(a0.x); v[1]=f2b(a0.y); v[2]=f2b(a0.z); v[3]=f2b(a0.w);
    v[4]=f2b(a1.x); v[5]=f2b(a1.y); v[6]=f2b(a1.z); v[7]=f2b(a1.w);
    *(bf16x8*)&As[r][k0+seg*8] = v;
  }
  {
    int br = tid>>1, half = tid&1;
    #pragma unroll
    for (int j=0;j<4;j++)
      *(bf16x8*)&Bs[br][half*32+j*8] = *(const bf16x8*)(wb + (size_t)br*64 + half*32 + j*8);
  }
  __syncthreads();
  int lane = tid&63, w = tid>>6;
  int wr = (w>>1)*32, wc = (w&1)*64;
  int fr = lane&15, fq = lane>>4;
  f32x4 acc[2][4] = {};
  #pragma unroll
  for (int k0=0;k0<64;k0+=32){
    bf16x8 a0 = *(bf16x8*)&As[wr+fr][k0+fq*8];
    bf16x8 a1 = *(bf16x8*)&As[wr+16+fr][k0+fq*8];
    #pragma unroll
    for (int nf=0;nf<4;nf++){
      bf16x8 bb = *(bf16x8*)&Bs[wc+nf*16+fr][k0+fq*8];
      acc[0][nf] = __builtin_amdgcn_mfma_f32_16x16x32_bf16(a0, bb, acc[0][nf], 0,0,0);
      acc[1][nf] = __builtin_amdgcn_mfma_f32_16x16x32_bf16(a1, bb, acc[1][nf], 0,0,0);
    }
  }
  #pragma unroll
  for (int mf=0;mf<2;mf++)
    #pragma unroll
    for (int nf=0;nf<4;nf++)
      #pragma unroll
      for (int q=0;q<4;q++){
        int grow = wr + mf*16 + fq*4 + q;
        int gcol = wc + nf*16 + fr;
        float v = acc[mf][nf][q] + bias[gcol];
        h[(size_t)(row0+grow)*D_MODEL + gcol] = v;
        hls[grow][gcol] = v;
      }
  __syncthreads();
  int row = tid&63, grp = tid>>6;
  float ps=0.f, pq=0.f;
  #pragma unroll
  for (int j=0;j<32;j++){ float xv = hls[row][grp*32+j]; ps += xv; pq += xv*xv; }
  psum[grp][row]=ps; psumsq[grp][row]=pq;
  __syncthreads();
  if (tid < 64){
    float S=0.f, Q=0.f;
    #pragma unroll
    for (int g=0;g<4;g++){ S+=psum[g][tid]; Q+=psumsq[g][tid]; }
    float mu = S*(1.f/128.f);
    mu_s[tid]=mu; rs_s[tid]=rsqrtf(Q*(1.f/128.f)-mu*mu+LN_EPS);
  }
  __syncthreads();
  #pragma unroll
  for (int j=0;j<32;j++){
    int c = grp*32+j;
    float o = (hls[row][c]-mu_s[row])*rs_s[row]*lnw[c]+lnb[c];
    hnbf[(size_t)(row0+row)*D_MODEL + c] = __float2bfloat16(o);
  }
}

// ---------------- bf16 MFMA GEMM ----------------
#define EPI_SPLITZ   0   /* cols<256 -> C bf16; cols>=256 -> C2 bf16 silu */
#define EPI_BMDT     1   /* cols<256 -> C bf16 softplus(+bias); cols>=256 -> C2(Bm) fp32 */

template<int EPI>
__global__ __launch_bounds__(256) void mfma_gemm(
    const __hip_bfloat16* __restrict__ Aptr, const __hip_bfloat16* __restrict__ Bt,
    const float* __restrict__ bias, void* __restrict__ Cptr, void* __restrict__ C2ptr,
    int lda, int K, int Nvalid){
  __shared__ __align__(16) short As[64][40];
  __shared__ __align__(16) short Bs[64][40];
  int tid = threadIdx.x;
  int row0 = blockIdx.y * 64, col0 = blockIdx.x * 64;
  int r = tid >> 2, seg = tid & 3;
  int lane = tid & 63, w = tid >> 6;
  int wr = (w >> 1) * 32, wc = (w & 1) * 32;
  int fr = lane & 15, fq = lane >> 4;
  f32x4 acc00 = {}, acc01 = {}, acc10 = {}, acc11 = {};
  for (int k0 = 0; k0 < K; k0 += 32){
    *(bf16x8*)&As[r][seg*8] = *(const bf16x8*)(Aptr + (size_t)(row0+r)*lda + k0 + seg*8);
    bf16x8 bv = {};
    if (col0 + r < Nvalid)
      bv = *(const bf16x8*)(Bt + (size_t)(col0+r)*K + k0 + seg*8);
    *(bf16x8*)&Bs[r][seg*8] = bv;
    __syncthreads();
    bf16x8 a0 = *(bf16x8*)&As[wr + fr][fq*8];
    bf16x8 a1 = *(bf16x8*)&As[wr + 16 + fr][fq*8];
    bf16x8 b0 = *(bf16x8*)&Bs[wc + fr][fq*8];
    bf16x8 b1 = *(bf16x8*)&Bs[wc + 16 + fr][fq*8];
    acc00 = __builtin_amdgcn_mfma_f32_16x16x32_bf16(a0, b0, acc00, 0, 0, 0);
    acc01 = __builtin_amdgcn_mfma_f32_16x16x32_bf16(a0, b1, acc01, 0, 0, 0);
    acc10 = __builtin_amdgcn_mfma_f32_16x16x32_bf16(a1, b0, acc10, 0, 0, 0);
    acc11 = __builtin_amdgcn_mfma_f32_16x16x32_bf16(a1, b1, acc11, 0, 0, 0);
    __syncthreads();
  }
  f32x4 accs[2][2] = {{acc00, acc01},{acc10, acc11}};
  #pragma unroll
  for (int mr=0; mr<2; mr++){
    #pragma unroll
    for (int nc2=0; nc2<2; nc2++){
      int gcol = col0 + wc + nc2*16 + fr;
      if (gcol < Nvalid){
        #pragma unroll
        for (int q=0; q<4; q++){
          int grow = row0 + wr + mr*16 + fq*4 + q;
          float v = accs[mr][nc2][q];
          if (EPI == EPI_SPLITZ){
            if (gcol < D_INNER)
              ((__hip_bfloat16*)Cptr)[(size_t)grow*D_INNER + gcol] = __float2bfloat16(v);
            else
              ((__hip_bfloat16*)C2ptr)[(size_t)grow*D_INNER + gcol - D_INNER] = __float2bfloat16(siluf(v));
          } else {
            if (gcol < D_INNER)
              ((__hip_bfloat16*)Cptr)[(size_t)grow*D_INNER + gcol] = __float2bfloat16(softplusf(v + bias[gcol]));
            else
              ((float*)C2ptr)[(size_t)grow*D_STATE + gcol - D_INNER] = v;
          }
        }
      }
    }
  }
}

// ---------------- Causal depthwise conv1d(K=4) + bias + silu, bf16 in/out ----------------
__global__ __launch_bounds__(256) void conv_silu_kernel(
    const __hip_bfloat16* __restrict__ xraw, const float* __restrict__ cw,
    const float* __restrict__ cb, __hip_bfloat16* __restrict__ xi){
  int g = blockIdx.x*256 + threadIdx.x;   // NTOK*32 threads, 8 channels each
  int t = g >> 5;
  int d0 = (g & 31) << 3;
  int l = t & (SEQ-1);
  float acc[8];
  #pragma unroll
  for (int j=0;j<8;j++) acc[j] = cb[d0+j];
  #pragma unroll
  for (int k=0;k<D_CONVK;k++){
    int ls = l + k - (D_CONVK-1);
    if (ls >= 0){
      bf16x8 v = *(const bf16x8*)(xraw + (size_t)(t - (D_CONVK-1) + k)*D_INNER + d0);
      #pragma unroll
      for (int j=0;j<8;j++)
        acc[j] = fmaf(b2f(v[j]), cw[(d0+j)*D_CONVK + k], acc[j]);
    }
  }
  bf16x8 o;
  #pragma unroll
  for (int j=0;j<8;j++) o[j] = f2b(siluf(acc[j]));
  *(bf16x8*)(xi + (size_t)t*D_INNER + d0) = o;
}

// ---------------- Chunked selective scan: phase 1 & 2 ----------------
__global__ __launch_bounds__(256) void scan_p1(
    const __hip_bfloat16* __restrict__ delta, const __hip_bfloat16* __restrict__ xi,
    const float* __restrict__ Bm, const float* __restrict__ A_log,
    float* __restrict__ cs, float* __restrict__ sumdlt){
  int bc = blockIdx.x;               // b*NC + c
  int c = bc & (NC-1);
  int b = bc >> 5;
  int d = threadIdx.x;
  float Aa[D_STATE];
  #pragma unroll
  for (int n=0;n<D_STATE;n++) Aa[n] = -__expf(A_log[d*D_STATE + n]);
  float s[D_STATE] = {};
  float sd = 0.f;
  size_t t0 = (size_t)b*SEQ + (size_t)c*CL;
  #pragma unroll 4
  for (int l=0; l<CL; l++){
    size_t t = t0 + l;
    float dlt = __bfloat162float(delta[t*D_INNER + d]);
    float xv  = __bfloat162float(xi[t*D_INNER + d]);
    const float4* bmr = (const float4*)(Bm + t*D_STATE);
    float4 q0=bmr[0], q1=bmr[1], q2=bmr[2], q3=bmr[3];
    float bm[D_STATE] = {q0.x,q0.y,q0.z,q0.w, q1.x,q1.y,q1.z,q1.w,
                         q2.x,q2.y,q2.z,q2.w, q3.x,q3.y,q3.z,q3.w};
    sd += dlt;
    float dx = dlt * xv;
    #pragma unroll
    for (int n=0;n<D_STATE;n++)
      s[n] = fmaf(__expf(dlt * Aa[n]), s[n], dx * bm[n]);
  }
  float4* out = (float4*)(cs + ((size_t)bc*D_INNER + d)*D_STATE);
  out[0] = make_float4(s[0],s[1],s[2],s[3]);
  out[1] = make_float4(s[4],s[5],s[6],s[7]);
  out[2] = make_float4(s[8],s[9],s[10],s[11]);
  out[3] = make_float4(s[12],s[13],s[14],s[15]);
  sumdlt[(size_t)bc*D_INNER + d] = sd;
}

__global__ __launch_bounds__(256) void scan_p2(
    const float* __restrict__ A_log, float* __restrict__ cs,
    const float* __restrict__ sumdlt){
  int b = blockIdx.x;
  int d = threadIdx.x;
  float Aa[D_STATE];
  #pragma unroll
  for (int n=0;n<D_STATE;n++) Aa[n] = -__expf(A_log[d*D_STATE + n]);
  float s[D_STATE] = {};
  #pragma unroll
  for (int c=0;c<NC;c++){
    size_t base = ((size_t)(b*NC + c)*D_INNER + d)*D_STATE;
    float4* p = (float4*)(cs + base);
    float4 e0=p[0], e1=p[1], e2=p[2], e3=p[3];
    float se[D_STATE] = {e0.x,e0.y,e0.z,e0.w, e1.x,e1.y,e1.z,e1.w,
                         e2.x,e2.y,e2.z,e2.w, e3.x,e3.y,e3.z,e3.w};
    float sd = sumdlt[(size_t)(b*NC + c)*D_INNER + d];
    float sin_[D_STATE];
    #pragma unroll
    for (int n=0;n<D_STATE;n++){
      sin_[n] = s[n];
      s[n] = fmaf(__expf(Aa[n]*sd), s[n], se[n]);
    }
    p[0] = make_float4(sin_[0],sin_[1],sin_[2],sin_[3]);
    p[1] = make_float4(sin_[4],sin_[5],sin_[6],sin_[7]);
    p[2] = make_float4(sin_[8],sin_[9],sin_[10],sin_[11]);
    p[3] = make_float4(sin_[12],sin_[13],sin_[14],sin_[15]);
  }
}

// ---------------- Fused: scan phase-3 + out-proj GEMM + residual + LN ----------------
// block = 32 tokens x 256 channels. MODE 0: write h fp32 raw + hnbf = LN(h, lnw).
// MODE 1 (last layer): write h = LN(h_raw, lnw) fp32 only.
template<int MODE>
__global__ __launch_bounds__(256) void scan_out_kernel(
    const __hip_bfloat16* __restrict__ dlt, const __hip_bfloat16* __restrict__ xi,
    const float* __restrict__ Bm, const __hip_bfloat16* __restrict__ zs,
    const float* __restrict__ A_log, const float* __restrict__ Dp,
    const float* __restrict__ cs, const __hip_bfloat16* __restrict__ wout,
    float* __restrict__ h, __hip_bfloat16* __restrict__ hnbf,
    const float* __restrict__ lnw, const float* __restrict__ lnb){
  __shared__ __align__(16) short ylds[32][264];   // aliased later as float hls[32][132]
  __shared__ float psum[8][32], psumsq[8][32], mu_s[32], rs_s[32];
  int blk = blockIdx.x;                 // b*NC + ct
  int b = blk >> 5, ct = blk & 31;
  int tid = threadIdx.x;
  int d = tid;
  // ---- scan phase ----
  float Aa[D_STATE];
  #pragma unroll
  for (int n=0;n<D_STATE;n++) Aa[n] = -__expf(A_log[d*D_STATE + n]);
  float Dv = Dp[d];
  const float4* sp = (const float4*)(cs + ((size_t)blk*D_INNER + d)*D_STATE);
  float4 s0=sp[0], s1=sp[1], s2=sp[2], s3=sp[3];
  float s[D_STATE] = {s0.x,s0.y,s0.z,s0.w, s1.x,s1.y,s1.z,s1.w,
                      s2.x,s2.y,s2.z,s2.w, s3.x,s3.y,s3.z,s3.w};
  size_t t0 = (size_t)b*SEQ + (size_t)ct*CL;
  #pragma unroll 4
  for (int l=0; l<CL; l++){
    size_t t = t0 + l;
    float dl = __bfloat162float(dlt[t*D_INNER + d]);
    float xv = __bfloat162float(xi[t*D_INNER + d]);
    float zv = __bfloat162float(zs[t*D_INNER + d]);
    const float4* bmr = (const float4*)(Bm + t*D_STATE);
    float4 q0=bmr[0], q1=bmr[1], q2=bmr[2], q3=bmr[3];
    float bm[D_STATE] = {q0.x,q0.y,q0.z,q0.w, q1.x,q1.y,q1.z,q1.w,
                         q2.x,q2.y,q2.z,q2.w, q3.x,q3.y,q3.z,q3.w};
    float dx = dl * xv;
    float y = 0.f;
    #pragma unroll
    for (int n=0;n<D_STATE;n++){
      s[n] = fmaf(__expf(dl * Aa[n]), s[n], dx * bm[n]);
      y = fmaf(s[n], bm[n], y);
    }
    ylds[l][d] = f2b((y + Dv*xv) * zv);
  }
  __syncthreads();
  // ---- out-proj GEMM: C[32x128] = ylds[32x256] @ wout^T ----
  int lane = tid & 63, w = tid >> 6;
  int fr = lane & 15, fq = lane >> 4;
  f32x4 acc[2][2] = {};
  #pragma unroll
  for (int k0=0; k0<D_INNER; k0+=32){
    bf16x8 a0 = *(bf16x8*)&ylds[fr][k0 + fq*8];
    bf16x8 a1 = *(bf16x8*)&ylds[16+fr][k0 + fq*8];
    bf16x8 b0 = *(const bf16x8*)(wout + (size_t)(w*32+fr)*D_INNER + k0 + fq*8);
    bf16x8 b1 = *(const bf16x8*)(wout + (size_t)(w*32+16+fr)*D_INNER + k0 + fq*8);
    acc[0][0] = __builtin_amdgcn_mfma_f32_16x16x32_bf16(a0, b0, acc[0][0], 0,0,0);
    acc[0][1] = __builtin_amdgcn_mfma_f32_16x16x32_bf16(a0, b1, acc[0][1], 0,0,0);
    acc[1][0] = __builtin_amdgcn_mfma_f32_16x16x32_bf16(a1, b0, acc[1][0], 0,0,0);
    acc[1][1] = __builtin_amdgcn_mfma_f32_16x16x32_bf16(a1, b1, acc[1][1], 0,0,0);
  }
  __syncthreads();          // all ylds reads complete before alias-overwrite
  // ---- residual add (+ raw h write in MODE 0) into LDS fp32 ----
  float* hls = (float*)&ylds[0][0];     // [32][132]
  #pragma unroll
  for (int mf=0;mf<2;mf++)
    #pragma unroll
    for (int nf=0;nf<2;nf++)
      #pragma unroll
      for (int q=0;q<4;q++){
        int grow = mf*16 + fq*4 + q;
        int gcol = w*32 + nf*16 + fr;
        size_t gidx = (t0 + grow)*D_MODEL + gcol;
        float v = acc[mf][nf][q] + h[gidx];
        if (MODE == 0) h[gidx] = v;
        hls[grow*132 + gcol] = v;
      }
  __syncthreads();
  // ---- LN over the block's 32 rows ----
  int row = tid & 31, grp = tid >> 5;   // 8 groups x 16 cols
  float ps=0.f, pq=0.f;
  #pragma unroll
  for (int j=0;j<16;j++){ float xv = hls[row*132 + grp*16 + j]; ps += xv; pq += xv*xv; }
  psum[grp][row]=ps; psumsq[grp][row]=pq;
  __syncthreads();
  if (tid < 32){
    float S=0.f, Q=0.f;
    #pragma unroll
    for (int g=0;g<8;g++){ S+=psum[g][tid]; Q+=psumsq[g][tid]; }
    float mu = S*(1.f/128.f);
    mu_s[tid]=mu; rs_s[tid]=rsqrtf(Q*(1.f/128.f)-mu*mu+LN_EPS);
  }
  __syncthreads();
  #pragma unroll
  for (int j=0;j<16;j++){
    int c = grp*16 + j;
    float o = (hls[row*132+c]-mu_s[row])*rs_s[row]*lnw[c]+lnb[c];
    if (MODE == 0) hnbf[(t0+row)*D_MODEL + c] = __float2bfloat16(o);
    else           h[(t0+row)*D_MODEL + c] = o;
  }
}

extern "C" void kernel_launch(void* const* d_in, const int* in_sizes, int n_in,
                              void* d_out, int out_size, void* d_ws, size_t ws_size,
                              hipStream_t stream){
  const float* x      = (const float*)d_in[0];
  const float* inp_w  = (const float*)d_in[1];
  const float* inp_b  = (const float*)d_in[2];
  const float* ln_w   = (const float*)d_in[3];
  const float* ln_b   = (const float*)d_in[4];
  const float* in_w   = (const float*)d_in[5];
  const float* conv_w = (const float*)d_in[6];
  const float* conv_b = (const float*)d_in[7];
  const float* xproj_w= (const float*)d_in[8];
  const float* dt_w   = (const float*)d_in[9];
  const float* dt_b   = (const float*)d_in[10];
  const float* A_log  = (const float*)d_in[11];
  const float* Dp     = (const float*)d_in[12];
  const float* out_w  = (const float*)d_in[13];
  const float* fn_w   = (const float*)d_in[14];
  const float* fn_b   = (const float*)d_in[15];

  float* h = (float*)d_out;                          // (NTOK,128) residual stream

  __hip_bfloat16* xraw = (__hip_bfloat16*)d_ws;       // NTOK*256
  __hip_bfloat16* zs   = xraw + (size_t)NTOK*256;     // NTOK*256 (silu(z))
  __hip_bfloat16* xi   = zs   + (size_t)NTOK*256;     // NTOK*256
  __hip_bfloat16* dlt  = xi   + (size_t)NTOK*256;     // NTOK*256
  __hip_bfloat16* hnbf = dlt  + (size_t)NTOK*256;     // NTOK*128
  float* Bm    = (float*)(hnbf + (size_t)NTOK*128);   // NTOK*16
  float* cs    = Bm + (size_t)NTOK*16;                // 512*256*16
  float* sumdlt= cs + (size_t)BATCH*NC*D_INNER*D_STATE;
  __hip_bfloat16* w_inpT = (__hip_bfloat16*)(sumdlt + (size_t)BATCH*NC*D_INNER);
  __hip_bfloat16* w_inT  = w_inpT + 128*64;           // 2 * 512*128
  __hip_bfloat16* w_bdT  = w_inT  + 2*512*128;        // 2 * 272*256 (dt rows 0..255, Bm rows 256..271)
  __hip_bfloat16* w_outT = w_bdT  + 2*272*256;        // 2 * 128*256

  // ---- one fused weight convert+transpose dispatch ----
  CT ct;
  ct.src[0]=inp_w;        ct.dst[0]=w_inpT;              ct.lg2K[0]=6; ct.ld[0]=128; ct.coff[0]=0;
  ct.src[1]=in_w;         ct.dst[1]=w_inT;               ct.lg2K[1]=7; ct.ld[1]=512; ct.coff[1]=0;
  ct.src[2]=in_w+65536;   ct.dst[2]=w_inT+65536;         ct.lg2K[2]=7; ct.ld[2]=512; ct.coff[2]=0;
  ct.src[3]=dt_w;         ct.dst[3]=w_bdT;               ct.lg2K[3]=8; ct.ld[3]=256; ct.coff[3]=0;
  ct.src[4]=dt_w+65536;   ct.dst[4]=w_bdT+272*256;       ct.lg2K[4]=8; ct.ld[4]=256; ct.coff[4]=0;
  ct.src[5]=xproj_w;      ct.dst[5]=w_bdT+256*256;       ct.lg2K[5]=8; ct.ld[5]=32;  ct.coff[5]=16;
  ct.src[6]=xproj_w+8192; ct.dst[6]=w_bdT+272*256+256*256; ct.lg2K[6]=8; ct.ld[6]=32; ct.coff[6]=16;
  ct.src[7]=out_w;        ct.dst[7]=w_outT;              ct.lg2K[7]=8; ct.ld[7]=128; ct.coff[7]=0;
  ct.src[8]=out_w+32768;  ct.dst[8]=w_outT+32768;        ct.lg2K[8]=8; ct.ld[8]=128; ct.coff[8]=0;
  int bs[9] = {0,32,288,544,800,1056,1072,1088,1216};
  for (int i=0;i<9;i++) ct.bstart[i]=bs[i];
  convT_all<<<1344, 256, 0, stream>>>(ct);

  // h = x @ inp_w + inp_b, hnbf = LN0(h)
  inp_ln_kernel<<<NTOK/64, 256, 0, stream>>>(x, w_inpT, inp_b, h, hnbf, ln_w, ln_b);

  for (int i=0;i<N_LAYERS;i++){
    // xraw | zs = hnbf @ in_w  (K=128, N=512, silu on z half)
    mfma_gemm<EPI_SPLITZ><<<dim3(8, NTOK/64), 256, 0, stream>>>(
        hnbf, w_inT + (size_t)i*512*128, nullptr, xraw, zs, 128, 128, 512);
    conv_silu_kernel<<<NTOK/8, 256, 0, stream>>>(
        xraw, conv_w + i*D_INNER*D_CONVK, conv_b + i*D_INNER, xi);
    // dlt (softplus, bf16) | Bm (fp32) = xi @ [dt_w | xproj_B]  (K=256, N=272)
    mfma_gemm<EPI_BMDT><<<dim3(5, NTOK/64), 256, 0, stream>>>(
        xi, w_bdT + (size_t)i*272*256, dt_b + i*D_INNER, dlt, Bm, 256, 256, 272);
    const float* Al = A_log + (size_t)i*D_INNER*D_STATE;
    scan_p1<<<BATCH*NC, 256, 0, stream>>>(dlt, xi, Bm, Al, cs, sumdlt);
    scan_p2<<<BATCH, 256, 0, stream>>>(Al, cs, sumdlt);
    if (i == 0)
      scan_out_kernel<0><<<BATCH*NC, 256, 0, stream>>>(
          dlt, xi, Bm, zs, Al, Dp + i*D_INNER, cs, w_outT + (size_t)i*128*256,
          h, hnbf, ln_w + D_MODEL, ln_b + D_MODEL);
    else
      scan_out_kernel<1><<<BATCH*NC, 256, 0, stream>>>(
          dlt, xi, Bm, zs, Al, Dp + i*D_INNER, cs, w_outT + (size_t)i*128*256,
          h, nullptr, fn_w, fn_b);
  }
}

// Round 6
// 218.802 us; speedup vs baseline: 1.6263x; 1.4941x over previous
//
#include <hip/hip_runtime.h>
#include <hip/hip_bf16.h>
#include <cstddef>

#define BATCH   16
#define SEQ     1024
#define D_MODEL 128
#define D_STATE 16
#define D_CONVK 4
#define D_INNER 256
#define N_LAYERS 2
#define NTOK    (BATCH*SEQ)   /* 16384 */
#define LN_EPS  1e-5f
#define CL      32            /* scan chunk length */
#define NC      32            /* chunks per sequence */

typedef __attribute__((ext_vector_type(8))) short bf16x8;
typedef __attribute__((ext_vector_type(4))) float f32x4;

__device__ __forceinline__ float siluf(float v){ return v / (1.f + __expf(-v)); }
__device__ __forceinline__ float softplusf(float x){ return x > 20.f ? x : log1pf(__expf(x)); }
__device__ __forceinline__ short f2b(float f){
  __hip_bfloat16 h = __float2bfloat16(f);
  return *reinterpret_cast<short*>(&h);
}
__device__ __forceinline__ float b2f(short s){
  union { unsigned u; float f; } v; v.u = ((unsigned)(unsigned short)s) << 16; return v.f;
}

// ---------------- fused weight transpose+convert (all weights, one kernel) ----------------
struct CT {
  const float* src[9];
  __hip_bfloat16* dst[9];
  int lg2K[9], ld[9], coff[9];
  int bstart[9];
};
__global__ __launch_bounds__(256) void convT_all(CT c){
  int bid = blockIdx.x, r = 0;
  #pragma unroll
  for (int i=1;i<9;i++) r = (bid >= c.bstart[i]) ? i : r;
  int idx = (bid - c.bstart[r])*256 + threadIdx.x;
  int lg = c.lg2K[r];
  int k = idx & ((1<<lg)-1), n = idx >> lg;
  c.dst[r][idx] = __float2bfloat16(c.src[r][(size_t)k*c.ld[r] + c.coff[r] + n]);
}

// ---------------- fused input-proj GEMM + LN0 ----------------
__global__ __launch_bounds__(256) void inp_ln_kernel(
    const float* __restrict__ x, const __hip_bfloat16* __restrict__ wb,
    const float* __restrict__ bias, float* __restrict__ h,
    __hip_bfloat16* __restrict__ hnbf,
    const float* __restrict__ lnw, const float* __restrict__ lnb){
  __shared__ __align__(16) short As[64][72];
  __shared__ __align__(16) short Bs[128][72];
  __shared__ float hls[64][133];
  __shared__ float psum[4][64], psumsq[4][64], mu_s[64], rs_s[64];
  int tid = threadIdx.x;
  int row0 = blockIdx.x*64;
  int r = tid>>2, seg = tid&3;
  #pragma unroll
  for (int k0=0;k0<64;k0+=32){
    const float* Af = x + (size_t)(row0+r)*64 + k0 + seg*8;
    float4 a0 = *(const float4*)Af;
    float4 a1 = *(const float4*)(Af+4);
    bf16x8 v;
    v[0]=f2b(a0.x); v[1]=f2b(a0.y); v[2]=f2b(a0.z); v[3]=f2b(a0.w);
    v[4]=f2b(a1.x); v[5]=f2b(a1.y); v[6]=f2b(a1.z); v[7]=f2b(a1.w);
    *(bf16x8*)&As[r][k0+seg*8] = v;
  }
  {
    int br = tid>>1, half = tid&1;
    #pragma unroll
    for (int j=0;j<4;j++)
      *(bf16x8*)&Bs[br][half*32+j*8] = *(const bf16x8*)(wb + (size_t)br*64 + half*32 + j*8);
  }
  __syncthreads();
  int lane = tid&63, w = tid>>6;
  int wr = (w>>1)*32, wc = (w&1)*64;
  int fr = lane&15, fq = lane>>4;
  f32x4 acc[2][4] = {};
  #pragma unroll
  for (int k0=0;k0<64;k0+=32){
    bf16x8 a0 = *(bf16x8*)&As[wr+fr][k0+fq*8];
    bf16x8 a1 = *(bf16x8*)&As[wr+16+fr][k0+fq*8];
    #pragma unroll
    for (int nf=0;nf<4;nf++){
      bf16x8 bb = *(bf16x8*)&Bs[wc+nf*16+fr][k0+fq*8];
      acc[0][nf] = __builtin_amdgcn_mfma_f32_16x16x32_bf16(a0, bb, acc[0][nf], 0,0,0);
      acc[1][nf] = __builtin_amdgcn_mfma_f32_16x16x32_bf16(a1, bb, acc[1][nf], 0,0,0);
    }
  }
  #pragma unroll
  for (int mf=0;mf<2;mf++)
    #pragma unroll
    for (int nf=0;nf<4;nf++)
      #pragma unroll
      for (int q=0;q<4;q++){
        int grow = wr + mf*16 + fq*4 + q;
        int gcol = wc + nf*16 + fr;
        float v = acc[mf][nf][q] + bias[gcol];
        h[(size_t)(row0+grow)*D_MODEL + gcol] = v;
        hls[grow][gcol] = v;
      }
  __syncthreads();
  int row = tid&63, grp = tid>>6;
  float ps=0.f, pq=0.f;
  #pragma unroll
  for (int j=0;j<32;j++){ float xv = hls[row][grp*32+j]; ps += xv; pq += xv*xv; }
  psum[grp][row]=ps; psumsq[grp][row]=pq;
  __syncthreads();
  if (tid < 64){
    float S=0.f, Q=0.f;
    #pragma unroll
    for (int g=0;g<4;g++){ S+=psum[g][tid]; Q+=psumsq[g][tid]; }
    float mu = S*(1.f/128.f);
    mu_s[tid]=mu; rs_s[tid]=rsqrtf(Q*(1.f/128.f)-mu*mu+LN_EPS);
  }
  __syncthreads();
  #pragma unroll
  for (int j=0;j<32;j++){
    int c = grp*32+j;
    float o = (hls[row][c]-mu_s[row])*rs_s[row]*lnw[c]+lnb[c];
    hnbf[(size_t)(row0+row)*D_MODEL + c] = __float2bfloat16(o);
  }
}

// ---------------- MEGA kernel: in-proj GEMM + conv + silu + dt/Bm GEMM + local scan ----------------
// block = (b, seg): 64 tokens. 512 threads = 8 waves.
__global__ __launch_bounds__(512) void mega1(
    const __hip_bfloat16* __restrict__ hnbf,
    const __hip_bfloat16* __restrict__ w_in,   // [512][128]
    const __hip_bfloat16* __restrict__ w_bd,   // [272][256]
    const float* __restrict__ cw, const float* __restrict__ cb,
    const float* __restrict__ dt_b, const float* __restrict__ A_log,
    __hip_bfloat16* __restrict__ zs, __hip_bfloat16* __restrict__ xi,
    __hip_bfloat16* __restrict__ dltg, float* __restrict__ Bmg,
    float* __restrict__ cs, float* __restrict__ sumdlt){
  __shared__ __align__(16) short hn_s[67][136];
  __shared__ __align__(16) short xraw_s[67][264];   // rows = token-3..token+63; aliased by dlt_s
  __shared__ __align__(16) short xi_s[64][264];
  __shared__ __align__(16) float Bm_s[64][16];
  short* dlt_s = &xraw_s[0][0];                     // [64][264] after conv done

  int tid = threadIdx.x;
  int blk = blockIdx.x;                 // b*16 + seg
  int seg = blk & 15;
  int b = blk >> 4;
  size_t t0 = (size_t)b*SEQ + (size_t)seg*64;

  // ---- stage hn rows (t0-3 .. t0+63) -> hn_s[0..66] ----
  for (int idx = tid; idx < 67*16; idx += 512){
    int r = idx >> 4, c8 = (idx & 15)*8;
    bf16x8 v = {0,0,0,0,0,0,0,0};
    if (!(seg == 0 && r < 3))
      v = *(const bf16x8*)(hnbf + (t0 - 3 + r)*D_MODEL + c8);
    *(bf16x8*)&hn_s[r][c8] = v;
  }
  __syncthreads();

  // ---- halo: xraw rows 0..2 (tokens t0-3..t0-1), cols 0..255, VALU dots ----
  #pragma unroll
  for (int rep = 0; rep < 2; rep++){
    int idx = rep*512 + tid;
    if (idx < 768){
      int r = idx >> 8, n = idx & 255;
      float acc = 0.f;
      if (seg != 0){
        const __hip_bfloat16* wrow = w_in + (size_t)n*128;
        #pragma unroll
        for (int k = 0; k < 128; k += 8){
          bf16x8 wv = *(const bf16x8*)(wrow + k);
          #pragma unroll
          for (int j = 0; j < 8; j++)
            acc = fmaf(b2f(hn_s[r][k+j]), b2f(wv[j]), acc);
        }
      }
      xraw_s[r][n] = f2b(acc);
    }
  }

  // ---- GEMM1: rows = tokens t0..t0+63 (hn_s rows 3..66), wave w -> cols w*64..w*64+63 ----
  int w = tid >> 6, lane = tid & 63;
  int fr = lane & 15, fq = lane >> 4;
  {
    bf16x8 A[4][4];
    #pragma unroll
    for (int mt=0;mt<4;mt++)
      #pragma unroll
      for (int kf=0;kf<4;kf++)
        A[mt][kf] = *(bf16x8*)&hn_s[3 + mt*16 + fr][kf*32 + fq*8];
    int col0 = w*64;
    #pragma unroll
    for (int nf=0;nf<4;nf++){
      int n0 = col0 + nf*16;
      bf16x8 Bfr[4];
      #pragma unroll
      for (int kf=0;kf<4;kf++)
        Bfr[kf] = *(const bf16x8*)(w_in + (size_t)(n0+fr)*128 + kf*32 + fq*8);
      #pragma unroll
      for (int mt=0;mt<4;mt++){
        f32x4 a = {0.f,0.f,0.f,0.f};
        #pragma unroll
        for (int kf=0;kf<4;kf++)
          a = __builtin_amdgcn_mfma_f32_16x16x32_bf16(A[mt][kf], Bfr[kf], a, 0,0,0);
        #pragma unroll
        for (int q=0;q<4;q++){
          int row = mt*16 + fq*4 + q;     // token offset 0..63
          int col = n0 + fr;
          float v = a[q];
          if (col < D_INNER)
            xraw_s[row+3][col] = f2b(v);
          else
            zs[(t0+row)*D_INNER + (col - D_INNER)] = __float2bfloat16(siluf(v));
        }
      }
    }
  }
  __syncthreads();

  // ---- conv(K=4) + bias + silu -> xi_s + xi global ----
  #pragma unroll
  for (int rep=0;rep<4;rep++){
    int item = rep*512 + tid;           // 2048 items = 64 tok x 32 dgroups
    int tok = item >> 5, d0 = (item & 31)*8;
    float acc[8];
    #pragma unroll
    for (int j=0;j<8;j++) acc[j] = cb[d0+j];
    #pragma unroll
    for (int k=0;k<D_CONVK;k++){
      bf16x8 v = *(bf16x8*)&xraw_s[tok + k][d0];
      #pragma unroll
      for (int j=0;j<8;j++)
        acc[j] = fmaf(b2f(v[j]), cw[(d0+j)*D_CONVK + k], acc[j]);
    }
    bf16x8 o;
    #pragma unroll
    for (int j=0;j<8;j++) o[j] = f2b(siluf(acc[j]));
    *(bf16x8*)&xi_s[tok][d0] = o;
    *(bf16x8*)(xi + (t0+tok)*D_INNER + d0) = o;
  }
  __syncthreads();

  // ---- GEMM2: dlt(softplus)|Bm = xi_s[64x256] @ w_bd[272x256]^T ----
  {
    int nfc = (w==7) ? 3 : 2;
    f32x4 acc2[3][4] = {};
    for (int kf=0;kf<8;kf++){
      bf16x8 A2[4];
      #pragma unroll
      for (int mt=0;mt<4;mt++)
        A2[mt] = *(bf16x8*)&xi_s[mt*16+fr][kf*32 + fq*8];
      #pragma unroll
      for (int nfi=0;nfi<3;nfi++){
        if (nfi < nfc){
          int nfrag = (nfi==2) ? 16 : 2*w + nfi;
          bf16x8 Bv = *(const bf16x8*)(w_bd + (size_t)(nfrag*16+fr)*256 + kf*32 + fq*8);
          #pragma unroll
          for (int mt=0;mt<4;mt++)
            acc2[nfi][mt] = __builtin_amdgcn_mfma_f32_16x16x32_bf16(A2[mt], Bv, acc2[nfi][mt], 0,0,0);
        }
      }
    }
    __syncthreads();   // conv reads of xraw_s done everywhere before dlt_s alias writes
    #pragma unroll
    for (int nfi=0;nfi<3;nfi++){
      if (nfi < nfc){
        int nfrag = (nfi==2) ? 16 : 2*w + nfi;
        #pragma unroll
        for (int mt=0;mt<4;mt++)
          #pragma unroll
          for (int q=0;q<4;q++){
            int row = mt*16 + fq*4 + q;
            float v = acc2[nfi][mt][q];
            if (nfrag < 16){
              int col = nfrag*16 + fr;
              float sp = softplusf(v + dt_b[col]);
              short sbits = f2b(sp);
              dlt_s[row*264 + col] = sbits;
              dltg[(t0+row)*D_INNER + col] = __float2bfloat16(sp);
            } else {
              Bm_s[row][fr] = v;
              Bmg[(t0+row)*D_STATE + fr] = v;
            }
          }
      }
    }
  }
  __syncthreads();

  // ---- local scan (p1): 2 chunks x 256 channels, all from LDS ----
  {
    int ct = tid >> 8, d = tid & 255;
    float Aa[D_STATE];
    #pragma unroll
    for (int n=0;n<D_STATE;n++) Aa[n] = -__expf(A_log[d*D_STATE + n]);
    float s[D_STATE] = {};
    float sd = 0.f;
    #pragma unroll 4
    for (int l=0; l<CL; l++){
      int row = ct*CL + l;
      float dl = b2f(dlt_s[row*264 + d]);
      float xv = b2f(xi_s[row][d]);
      const float4* bmp = (const float4*)&Bm_s[row][0];
      float4 q0=bmp[0], q1=bmp[1], q2=bmp[2], q3=bmp[3];
      float bm[D_STATE] = {q0.x,q0.y,q0.z,q0.w, q1.x,q1.y,q1.z,q1.w,
                           q2.x,q2.y,q2.z,q2.w, q3.x,q3.y,q3.z,q3.w};
      sd += dl;
      float dx = dl * xv;
      #pragma unroll
      for (int n=0;n<D_STATE;n++)
        s[n] = fmaf(__expf(dl * Aa[n]), s[n], dx * bm[n]);
    }
    int bc = b*NC + seg*2 + ct;
    float4* out = (float4*)(cs + ((size_t)bc*D_INNER + d)*D_STATE);
    out[0] = make_float4(s[0],s[1],s[2],s[3]);
    out[1] = make_float4(s[4],s[5],s[6],s[7]);
    out[2] = make_float4(s[8],s[9],s[10],s[11]);
    out[3] = make_float4(s[12],s[13],s[14],s[15]);
    sumdlt[(size_t)bc*D_INNER + d] = sd;
  }
}

// ---------------- chunk combine: one thread per (b,d,n) chain ----------------
__global__ __launch_bounds__(256) void scan_p2(
    const float* __restrict__ A_log, float* __restrict__ cs,
    const float* __restrict__ sumdlt){
  int b = blockIdx.x >> 4;
  int dhi = blockIdx.x & 15;
  int d = dhi*16 + (threadIdx.x >> 4);
  int n = threadIdx.x & 15;
  float Aa = -__expf(A_log[d*D_STATE + n]);
  float s = 0.f;
  for (int c=0;c<NC;c++){
    size_t bc = (size_t)b*NC + c;
    float se = cs[(bc*D_INNER + d)*D_STATE + n];
    float sd = sumdlt[bc*D_INNER + d];
    cs[(bc*D_INNER + d)*D_STATE + n] = s;
    s = fmaf(__expf(Aa*sd), s, se);
  }
}

// ---------------- Fused: scan phase-3 + out-proj GEMM + residual + LN ----------------
template<int MODE>
__global__ __launch_bounds__(256) void scan_out_kernel(
    const __hip_bfloat16* __restrict__ dlt, const __hip_bfloat16* __restrict__ xi,
    const float* __restrict__ Bm, const __hip_bfloat16* __restrict__ zs,
    const float* __restrict__ A_log, const float* __restrict__ Dp,
    const float* __restrict__ cs, const __hip_bfloat16* __restrict__ wout,
    float* __restrict__ h, __hip_bfloat16* __restrict__ hnbf,
    const float* __restrict__ lnw, const float* __restrict__ lnb){
  __shared__ __align__(16) short ylds[32][264];   // aliased later as float hls[32][132]
  __shared__ float psum[8][32], psumsq[8][32], mu_s[32], rs_s[32];
  int blk = blockIdx.x;                 // b*NC + ct
  int b = blk >> 5, ct = blk & 31;
  int tid = threadIdx.x;
  int d = tid;
  float Aa[D_STATE];
  #pragma unroll
  for (int n=0;n<D_STATE;n++) Aa[n] = -__expf(A_log[d*D_STATE + n]);
  float Dv = Dp[d];
  const float4* sp = (const float4*)(cs + ((size_t)blk*D_INNER + d)*D_STATE);
  float4 s0=sp[0], s1=sp[1], s2=sp[2], s3=sp[3];
  float s[D_STATE] = {s0.x,s0.y,s0.z,s0.w, s1.x,s1.y,s1.z,s1.w,
                      s2.x,s2.y,s2.z,s2.w, s3.x,s3.y,s3.z,s3.w};
  size_t t0 = (size_t)b*SEQ + (size_t)ct*CL;
  #pragma unroll 4
  for (int l=0; l<CL; l++){
    size_t t = t0 + l;
    float dl = __bfloat162float(dlt[t*D_INNER + d]);
    float xv = __bfloat162float(xi[t*D_INNER + d]);
    float zv = __bfloat162float(zs[t*D_INNER + d]);
    const float4* bmr = (const float4*)(Bm + t*D_STATE);
    float4 q0=bmr[0], q1=bmr[1], q2=bmr[2], q3=bmr[3];
    float bm[D_STATE] = {q0.x,q0.y,q0.z,q0.w, q1.x,q1.y,q1.z,q1.w,
                         q2.x,q2.y,q2.z,q2.w, q3.x,q3.y,q3.z,q3.w};
    float dx = dl * xv;
    float y = 0.f;
    #pragma unroll
    for (int n=0;n<D_STATE;n++){
      s[n] = fmaf(__expf(dl * Aa[n]), s[n], dx * bm[n]);
      y = fmaf(s[n], bm[n], y);
    }
    ylds[l][d] = f2b((y + Dv*xv) * zv);
  }
  __syncthreads();
  int lane = tid & 63, w = tid >> 6;
  int fr = lane & 15, fq = lane >> 4;
  f32x4 acc[2][2] = {};
  #pragma unroll
  for (int k0=0; k0<D_INNER; k0+=32){
    bf16x8 a0 = *(bf16x8*)&ylds[fr][k0 + fq*8];
    bf16x8 a1 = *(bf16x8*)&ylds[16+fr][k0 + fq*8];
    bf16x8 b0 = *(const bf16x8*)(wout + (size_t)(w*32+fr)*D_INNER + k0 + fq*8);
    bf16x8 b1 = *(const bf16x8*)(wout + (size_t)(w*32+16+fr)*D_INNER + k0 + fq*8);
    acc[0][0] = __builtin_amdgcn_mfma_f32_16x16x32_bf16(a0, b0, acc[0][0], 0,0,0);
    acc[0][1] = __builtin_amdgcn_mfma_f32_16x16x32_bf16(a0, b1, acc[0][1], 0,0,0);
    acc[1][0] = __builtin_amdgcn_mfma_f32_16x16x32_bf16(a1, b0, acc[1][0], 0,0,0);
    acc[1][1] = __builtin_amdgcn_mfma_f32_16x16x32_bf16(a1, b1, acc[1][1], 0,0,0);
  }
  __syncthreads();
  float* hls = (float*)&ylds[0][0];     // [32][132]
  #pragma unroll
  for (int mf=0;mf<2;mf++)
    #pragma unroll
    for (int nf=0;nf<2;nf++)
      #pragma unroll
      for (int q=0;q<4;q++){
        int grow = mf*16 + fq*4 + q;
        int gcol = w*32 + nf*16 + fr;
        size_t gidx = (t0 + grow)*D_MODEL + gcol;
        float v = acc[mf][nf][q] + h[gidx];
        if (MODE == 0) h[gidx] = v;
        hls[grow*132 + gcol] = v;
      }
  __syncthreads();
  int row = tid & 31, grp = tid >> 5;
  float ps=0.f, pq=0.f;
  #pragma unroll
  for (int j=0;j<16;j++){ float xv = hls[row*132 + grp*16 + j]; ps += xv; pq += xv*xv; }
  psum[grp][row]=ps; psumsq[grp][row]=pq;
  __syncthreads();
  if (tid < 32){
    float S=0.f, Q=0.f;
    #pragma unroll
    for (int g=0;g<8;g++){ S+=psum[g][tid]; Q+=psumsq[g][tid]; }
    float mu = S*(1.f/128.f);
    mu_s[tid]=mu; rs_s[tid]=rsqrtf(Q*(1.f/128.f)-mu*mu+LN_EPS);
  }
  __syncthreads();
  #pragma unroll
  for (int j=0;j<16;j++){
    int c = grp*16 + j;
    float o = (hls[row*132+c]-mu_s[row])*rs_s[row]*lnw[c]+lnb[c];
    if (MODE == 0) hnbf[(t0+row)*D_MODEL + c] = __float2bfloat16(o);
    else           h[(t0+row)*D_MODEL + c] = o;
  }
}

extern "C" void kernel_launch(void* const* d_in, const int* in_sizes, int n_in,
                              void* d_out, int out_size, void* d_ws, size_t ws_size,
                              hipStream_t stream){
  const float* x      = (const float*)d_in[0];
  const float* inp_w  = (const float*)d_in[1];
  const float* inp_b  = (const float*)d_in[2];
  const float* ln_w   = (const float*)d_in[3];
  const float* ln_b   = (const float*)d_in[4];
  const float* in_w   = (const float*)d_in[5];
  const float* conv_w = (const float*)d_in[6];
  const float* conv_b = (const float*)d_in[7];
  const float* xproj_w= (const float*)d_in[8];
  const float* dt_w   = (const float*)d_in[9];
  const float* dt_b   = (const float*)d_in[10];
  const float* A_log  = (const float*)d_in[11];
  const float* Dp     = (const float*)d_in[12];
  const float* out_w  = (const float*)d_in[13];
  const float* fn_w   = (const float*)d_in[14];
  const float* fn_b   = (const float*)d_in[15];

  float* h = (float*)d_out;                           // (NTOK,128) residual stream

  __hip_bfloat16* zs   = (__hip_bfloat16*)d_ws;       // NTOK*256 (silu(z))
  __hip_bfloat16* xi   = zs   + (size_t)NTOK*256;     // NTOK*256
  __hip_bfloat16* dlt  = xi   + (size_t)NTOK*256;     // NTOK*256
  __hip_bfloat16* hnbf = dlt  + (size_t)NTOK*256;     // NTOK*128
  float* Bm    = (float*)(hnbf + (size_t)NTOK*128);   // NTOK*16
  float* cs    = Bm + (size_t)NTOK*16;                // 512*256*16
  float* sumdlt= cs + (size_t)BATCH*NC*D_INNER*D_STATE;
  __hip_bfloat16* w_inpT = (__hip_bfloat16*)(sumdlt + (size_t)BATCH*NC*D_INNER);
  __hip_bfloat16* w_inT  = w_inpT + 128*64;           // 2 * 512*128
  __hip_bfloat16* w_bdT  = w_inT  + 2*512*128;        // 2 * 272*256
  __hip_bfloat16* w_outT = w_bdT  + 2*272*256;        // 2 * 128*256

  CT ct;
  ct.src[0]=inp_w;        ct.dst[0]=w_inpT;              ct.lg2K[0]=6; ct.ld[0]=128; ct.coff[0]=0;
  ct.src[1]=in_w;         ct.dst[1]=w_inT;               ct.lg2K[1]=7; ct.ld[1]=512; ct.coff[1]=0;
  ct.src[2]=in_w+65536;   ct.dst[2]=w_inT+65536;         ct.lg2K[2]=7; ct.ld[2]=512; ct.coff[2]=0;
  ct.src[3]=dt_w;         ct.dst[3]=w_bdT;               ct.lg2K[3]=8; ct.ld[3]=256; ct.coff[3]=0;
  ct.src[4]=dt_w+65536;   ct.dst[4]=w_bdT+272*256;       ct.lg2K[4]=8; ct.ld[4]=256; ct.coff[4]=0;
  ct.src[5]=xproj_w;      ct.dst[5]=w_bdT+256*256;       ct.lg2K[5]=8; ct.ld[5]=32;  ct.coff[5]=16;
  ct.src[6]=xproj_w+8192; ct.dst[6]=w_bdT+272*256+256*256; ct.lg2K[6]=8; ct.ld[6]=32; ct.coff[6]=16;
  ct.src[7]=out_w;        ct.dst[7]=w_outT;              ct.lg2K[7]=8; ct.ld[7]=128; ct.coff[7]=0;
  ct.src[8]=out_w+32768;  ct.dst[8]=w_outT+32768;        ct.lg2K[8]=8; ct.ld[8]=128; ct.coff[8]=0;
  int bs[9] = {0,32,288,544,800,1056,1072,1088,1216};
  for (int i=0;i<9;i++) ct.bstart[i]=bs[i];
  convT_all<<<1344, 256, 0, stream>>>(ct);

  inp_ln_kernel<<<NTOK/64, 256, 0, stream>>>(x, w_inpT, inp_b, h, hnbf, ln_w, ln_b);

  for (int i=0;i<N_LAYERS;i++){
    const float* Al = A_log + (size_t)i*D_INNER*D_STATE;
    mega1<<<NTOK/64, 512, 0, stream>>>(
        hnbf, w_inT + (size_t)i*512*128, w_bdT + (size_t)i*272*256,
        conv_w + i*D_INNER*D_CONVK, conv_b + i*D_INNER,
        dt_b + i*D_INNER, Al,
        zs, xi, dlt, Bm, cs, sumdlt);
    scan_p2<<<256, 256, 0, stream>>>(Al, cs, sumdlt);
    if (i == 0)
      scan_out_kernel<0><<<BATCH*NC, 256, 0, stream>>>(
          dlt, xi, Bm, zs, Al, Dp + i*D_INNER, cs, w_outT + (size_t)i*128*256,
          h, hnbf, ln_w + D_MODEL, ln_b + D_MODEL);
    else
      scan_out_kernel<1><<<BATCH*NC, 256, 0, stream>>>(
          dlt, xi, Bm, zs, Al, Dp + i*D_INNER, cs, w_outT + (size_t)i*128*256,
          h, nullptr, fn_w, fn_b);
  }
}

// Round 7
// 214.244 us; speedup vs baseline: 1.6609x; 1.0213x over previous
//
#include <hip/hip_runtime.h>
#include <hip/hip_bf16.h>
#include <cstddef>

#define BATCH   16
#define SEQ     1024
#define D_MODEL 128
#define D_STATE 16
#define D_CONVK 4
#define D_INNER 256
#define N_LAYERS 2
#define NTOK    (BATCH*SEQ)   /* 16384 */
#define LN_EPS  1e-5f
#define CL      32            /* scan chunk length */
#define NC      32            /* chunks per sequence */

typedef __attribute__((ext_vector_type(8))) short bf16x8;
typedef __attribute__((ext_vector_type(4))) float f32x4;

__device__ __forceinline__ float siluf(float v){ return v / (1.f + __expf(-v)); }
__device__ __forceinline__ float softplusf(float x){ return x > 20.f ? x : log1pf(__expf(x)); }
__device__ __forceinline__ short f2b(float f){
  __hip_bfloat16 h = __float2bfloat16(f);
  return *reinterpret_cast<short*>(&h);
}
__device__ __forceinline__ float b2f(short s){
  union { unsigned u; float f; } v; v.u = ((unsigned)(unsigned short)s) << 16; return v.f;
}

// ---------------- fused weight transpose+convert (all weights, one kernel) ----------------
struct CT {
  const float* src[9];
  __hip_bfloat16* dst[9];
  int lg2K[9], ld[9], coff[9];
  int bstart[9];
};
__global__ __launch_bounds__(256) void convT_all(CT c){
  int bid = blockIdx.x, r = 0;
  #pragma unroll
  for (int i=1;i<9;i++) r = (bid >= c.bstart[i]) ? i : r;
  int idx = (bid - c.bstart[r])*256 + threadIdx.x;
  int lg = c.lg2K[r];
  int k = idx & ((1<<lg)-1), n = idx >> lg;
  c.dst[r][idx] = __float2bfloat16(c.src[r][(size_t)k*c.ld[r] + c.coff[r] + n]);
}

// ---------------- fused input-proj GEMM + LN0 ----------------
__global__ __launch_bounds__(256) void inp_ln_kernel(
    const float* __restrict__ x, const __hip_bfloat16* __restrict__ wb,
    const float* __restrict__ bias, float* __restrict__ h,
    __hip_bfloat16* __restrict__ hnbf,
    const float* __restrict__ lnw, const float* __restrict__ lnb){
  __shared__ __align__(16) short As[64][72];
  __shared__ __align__(16) short Bs[128][72];
  __shared__ float hls[64][133];
  __shared__ float psum[4][64], psumsq[4][64], mu_s[64], rs_s[64];
  int tid = threadIdx.x;
  int row0 = blockIdx.x*64;
  int r = tid>>2, seg = tid&3;
  #pragma unroll
  for (int k0=0;k0<64;k0+=32){
    const float* Af = x + (size_t)(row0+r)*64 + k0 + seg*8;
    float4 a0 = *(const float4*)Af;
    float4 a1 = *(const float4*)(Af+4);
    bf16x8 v;
    v[0]=f2b(a0.x); v[1]=f2b(a0.y); v[2]=f2b(a0.z); v[3]=f2b(a0.w);
    v[4]=f2b(a1.x); v[5]=f2b(a1.y); v[6]=f2b(a1.z); v[7]=f2b(a1.w);
    *(bf16x8*)&As[r][k0+seg*8] = v;
  }
  {
    int br = tid>>1, half = tid&1;
    #pragma unroll
    for (int j=0;j<4;j++)
      *(bf16x8*)&Bs[br][half*32+j*8] = *(const bf16x8*)(wb + (size_t)br*64 + half*32 + j*8);
  }
  __syncthreads();
  int lane = tid&63, w = tid>>6;
  int wr = (w>>1)*32, wc = (w&1)*64;
  int fr = lane&15, fq = lane>>4;
  f32x4 acc[2][4] = {};
  #pragma unroll
  for (int k0=0;k0<64;k0+=32){
    bf16x8 a0 = *(bf16x8*)&As[wr+fr][k0+fq*8];
    bf16x8 a1 = *(bf16x8*)&As[wr+16+fr][k0+fq*8];
    #pragma unroll
    for (int nf=0;nf<4;nf++){
      bf16x8 bb = *(bf16x8*)&Bs[wc+nf*16+fr][k0+fq*8];
      acc[0][nf] = __builtin_amdgcn_mfma_f32_16x16x32_bf16(a0, bb, acc[0][nf], 0,0,0);
      acc[1][nf] = __builtin_amdgcn_mfma_f32_16x16x32_bf16(a1, bb, acc[1][nf], 0,0,0);
    }
  }
  #pragma unroll
  for (int mf=0;mf<2;mf++)
    #pragma unroll
    for (int nf=0;nf<4;nf++)
      #pragma unroll
      for (int q=0;q<4;q++){
        int grow = wr + mf*16 + fq*4 + q;
        int gcol = wc + nf*16 + fr;
        float v = acc[mf][nf][q] + bias[gcol];
        h[(size_t)(row0+grow)*D_MODEL + gcol] = v;
        hls[grow][gcol] = v;
      }
  __syncthreads();
  int row = tid&63, grp = tid>>6;
  float ps=0.f, pq=0.f;
  #pragma unroll
  for (int j=0;j<32;j++){ float xv = hls[row][grp*32+j]; ps += xv; pq += xv*xv; }
  psum[grp][row]=ps; psumsq[grp][row]=pq;
  __syncthreads();
  if (tid < 64){
    float S=0.f, Q=0.f;
    #pragma unroll
    for (int g=0;g<4;g++){ S+=psum[g][tid]; Q+=psumsq[g][tid]; }
    float mu = S*(1.f/128.f);
    mu_s[tid]=mu; rs_s[tid]=rsqrtf(Q*(1.f/128.f)-mu*mu+LN_EPS);
  }
  __syncthreads();
  #pragma unroll
  for (int j=0;j<32;j++){
    int c = grp*32+j;
    float o = (hls[row][c]-mu_s[row])*rs_s[row]*lnw[c]+lnb[c];
    hnbf[(size_t)(row0+row)*D_MODEL + c] = __float2bfloat16(o);
  }
}

// ---------------- MEGA kernel (32-token tile): in-proj + conv + silu + dt/Bm + local scan ----------------
// grid = BATCH*NC = 512 blocks, 512 threads = 8 waves, ~37.4 KB LDS -> 2 blocks/CU
__global__ __launch_bounds__(512,4) void mega32(
    const __hip_bfloat16* __restrict__ hnbf,
    const __hip_bfloat16* __restrict__ w_in,   // [512][128]
    const __hip_bfloat16* __restrict__ w_bd,   // [272][256]
    const float* __restrict__ cw, const float* __restrict__ cb,
    const float* __restrict__ dt_b, const float* __restrict__ A_log,
    __hip_bfloat16* __restrict__ zs, __hip_bfloat16* __restrict__ xi,
    __hip_bfloat16* __restrict__ dltg, float* __restrict__ Bmg,
    float* __restrict__ cs, float* __restrict__ sumdlt){
  __shared__ __align__(16) short xraw_s[35][264];   // rows = tokens t0-3 .. t0+31; later aliased by dlt
  __shared__ __align__(16) short xi_s[32][264];
  __shared__ __align__(16) float Bm_s[32][16];
  short* dlt_s = &xraw_s[0][0];                     // [32][264] after conv done

  int tid = threadIdx.x;
  int blk = blockIdx.x;                 // b*NC + seg
  int seg = blk & 31;
  int b = blk >> 5;
  size_t t0 = (size_t)b*SEQ + (size_t)seg*CL;
  long tA0 = (long)t0 - 3;

  int w = tid >> 6, lane = tid & 63;
  int fr = lane & 15, fq = lane >> 4;

  // ---- GEMM1: rows t0-3..t0+44 (3 m-tiles, clamped), wave w -> cols w*64..w*64+63 of 512 ----
  {
    size_t arow[3];
    #pragma unroll
    for (int mt=0;mt<3;mt++){
      long tg = tA0 + mt*16 + fr;
      if (tg < 0) tg = 0;
      if (tg > NTOK-1) tg = NTOK-1;
      arow[mt] = (size_t)tg*D_MODEL + fq*8;
    }
    f32x4 acc1[3][4] = {};
    #pragma unroll
    for (int nf=0;nf<4;nf++){
      bf16x8 Bf[4];
      #pragma unroll
      for (int kf=0;kf<4;kf++)
        Bf[kf] = *(const bf16x8*)(w_in + (size_t)(w*64+nf*16+fr)*D_MODEL + kf*32 + fq*8);
      #pragma unroll
      for (int mt=0;mt<3;mt++){
        bf16x8 Af[4];
        #pragma unroll
        for (int kf=0;kf<4;kf++)
          Af[kf] = *(const bf16x8*)(hnbf + arow[mt] + kf*32);
        #pragma unroll
        for (int kf=0;kf<4;kf++)
          acc1[mt][nf] = __builtin_amdgcn_mfma_f32_16x16x32_bf16(Af[kf], Bf[kf], acc1[mt][nf], 0,0,0);
      }
    }
    #pragma unroll
    for (int mt=0;mt<3;mt++)
      #pragma unroll
      for (int nf=0;nf<4;nf++)
        #pragma unroll
        for (int q=0;q<4;q++){
          int row = mt*16 + fq*4 + q;       // 0..47, valid 0..34
          int col = w*64 + nf*16 + fr;
          float v = acc1[mt][nf][q];
          if (row < 35){
            if (col < D_INNER){
              xraw_s[row][col] = (seg==0 && row<3) ? (short)0 : f2b(v);
            } else if (row >= 3){
              zs[(t0 + row - 3)*D_INNER + (col - D_INNER)] = __float2bfloat16(siluf(v));
            }
          }
        }
  }
  __syncthreads();

  // ---- conv(K=4) + bias + silu -> xi_s + xi global ----
  #pragma unroll
  for (int rep=0;rep<2;rep++){
    int item = rep*512 + tid;             // 1024 = 32 tok x 32 dgroups
    int tok = item >> 5, d0 = (item & 31) << 3;
    float acc[8];
    #pragma unroll
    for (int j=0;j<8;j++) acc[j] = cb[d0+j];
    #pragma unroll
    for (int k=0;k<D_CONVK;k++){
      bf16x8 v = *(bf16x8*)&xraw_s[tok + k][d0];
      #pragma unroll
      for (int j=0;j<8;j++)
        acc[j] = fmaf(b2f(v[j]), cw[(d0+j)*D_CONVK + k], acc[j]);
    }
    bf16x8 o;
    #pragma unroll
    for (int j=0;j<8;j++) o[j] = f2b(siluf(acc[j]));
    *(bf16x8*)&xi_s[tok][d0] = o;
    *(bf16x8*)(xi + (t0+tok)*D_INNER + d0) = o;
  }
  __syncthreads();

  // ---- GEMM2: dlt(softplus)|Bm = xi_s[32x256] @ w_bd[272x256]^T ----
  {
    int nfc = (w==7) ? 3 : 2;
    f32x4 acc2[3][2] = {};
    for (int kf=0;kf<8;kf++){
      bf16x8 A2[2];
      #pragma unroll
      for (int mt=0;mt<2;mt++)
        A2[mt] = *(bf16x8*)&xi_s[mt*16+fr][kf*32 + fq*8];
      #pragma unroll
      for (int nfi=0;nfi<3;nfi++){
        if (nfi < nfc){
          int nfrag = (nfi==2) ? 16 : 2*w + nfi;
          bf16x8 Bv = *(const bf16x8*)(w_bd + (size_t)(nfrag*16+fr)*256 + kf*32 + fq*8);
          #pragma unroll
          for (int mt=0;mt<2;mt++)
            acc2[nfi][mt] = __builtin_amdgcn_mfma_f32_16x16x32_bf16(A2[mt], Bv, acc2[nfi][mt], 0,0,0);
        }
      }
    }
    #pragma unroll
    for (int nfi=0;nfi<3;nfi++){
      if (nfi < nfc){
        int nfrag = (nfi==2) ? 16 : 2*w + nfi;
        #pragma unroll
        for (int mt=0;mt<2;mt++)
          #pragma unroll
          for (int q=0;q<4;q++){
            int row = mt*16 + fq*4 + q;
            float v = acc2[nfi][mt][q];
            if (nfrag < 16){
              int col = nfrag*16 + fr;
              float sp = softplusf(v + dt_b[col]);
              dlt_s[row*264 + col] = f2b(sp);
              dltg[(t0+row)*D_INNER + col] = __float2bfloat16(sp);
            } else {
              Bm_s[row][fr] = v;
              Bmg[(t0+row)*D_STATE + fr] = v;
            }
          }
      }
    }
  }
  __syncthreads();

  // ---- local scan (p1): 1 chunk, 2 threads/channel (8 states each), all from LDS ----
  {
    int d = tid & 255, half = tid >> 8, n0 = half*8;
    float Aa[8];
    #pragma unroll
    for (int j=0;j<8;j++) Aa[j] = -__expf(A_log[d*D_STATE + n0 + j]);
    float s[8] = {};
    float sd = 0.f;
    #pragma unroll 4
    for (int l=0; l<CL; l++){
      float dl = b2f(dlt_s[l*264 + d]);
      float xv = b2f(xi_s[l][d]);
      const float4* bp = (const float4*)&Bm_s[l][n0];
      float4 b0 = bp[0], b1 = bp[1];
      float bm[8] = {b0.x,b0.y,b0.z,b0.w, b1.x,b1.y,b1.z,b1.w};
      sd += dl;
      float dx = dl * xv;
      #pragma unroll
      for (int j=0;j<8;j++)
        s[j] = fmaf(__expf(dl * Aa[j]), s[j], dx * bm[j]);
    }
    float4* outp = (float4*)(cs + ((size_t)blk*D_INNER + d)*D_STATE + n0);
    outp[0] = make_float4(s[0],s[1],s[2],s[3]);
    outp[1] = make_float4(s[4],s[5],s[6],s[7]);
    if (half == 0) sumdlt[(size_t)blk*D_INNER + d] = sd;
  }
}

// ---------------- chunk combine: one thread per (b,d,n) chain ----------------
__global__ __launch_bounds__(256) void scan_p2(
    const float* __restrict__ A_log, float* __restrict__ cs,
    const float* __restrict__ sumdlt){
  int b = blockIdx.x >> 4;
  int dhi = blockIdx.x & 15;
  int d = dhi*16 + (threadIdx.x >> 4);
  int n = threadIdx.x & 15;
  float Aa = -__expf(A_log[d*D_STATE + n]);
  float s = 0.f;
  for (int c=0;c<NC;c++){
    size_t bc = (size_t)b*NC + c;
    float se = cs[(bc*D_INNER + d)*D_STATE + n];
    float sd = sumdlt[bc*D_INNER + d];
    cs[(bc*D_INNER + d)*D_STATE + n] = s;
    s = fmaf(__expf(Aa*sd), s, se);
  }
}

// ---------------- Fused: scan phase-3 (state-halved) + out-proj GEMM + residual + LN ----------------
// 512 threads. MODE 0: h += y@W (raw) + hnbf = LN. MODE 1: h = LN(h_raw + y@W) final.
template<int MODE>
__global__ __launch_bounds__(512,4) void scan_out_kernel(
    const __hip_bfloat16* __restrict__ dlt, const __hip_bfloat16* __restrict__ xi,
    const float* __restrict__ Bm, const __hip_bfloat16* __restrict__ zs,
    const float* __restrict__ A_log, const float* __restrict__ Dp,
    const float* __restrict__ cs, const __hip_bfloat16* __restrict__ wout,
    float* __restrict__ h, __hip_bfloat16* __restrict__ hnbf,
    const float* __restrict__ lnw, const float* __restrict__ lnb){
  __shared__ __align__(16) short y0ls[32][264];   // aliased later as float hls[32][132]
  __shared__ __align__(16) short y1ls[32][264];
  __shared__ float psum[16][32], psumsq[16][32], mu_s[32], rs_s[32];
  int blk = blockIdx.x;                 // b*NC + ct
  int b = blk >> 5, ct = blk & 31;
  int tid = threadIdx.x;
  size_t t0 = (size_t)b*SEQ + (size_t)ct*CL;
  // ---- scan (2 threads per channel) ----
  {
    int d = tid & 255, half = tid >> 8, n0 = half*8;
    float Aa[8];
    #pragma unroll
    for (int j=0;j<8;j++) Aa[j] = -__expf(A_log[d*D_STATE + n0 + j]);
    float Dv = Dp[d];
    const float4* sp = (const float4*)(cs + ((size_t)blk*D_INNER + d)*D_STATE + n0);
    float4 s0=sp[0], s1=sp[1];
    float s[8] = {s0.x,s0.y,s0.z,s0.w, s1.x,s1.y,s1.z,s1.w};
    #pragma unroll 4
    for (int l=0; l<CL; l++){
      size_t t = t0 + l;
      float dl = __bfloat162float(dlt[t*D_INNER + d]);
      float xv = __bfloat162float(xi[t*D_INNER + d]);
      float zv = __bfloat162float(zs[t*D_INNER + d]);
      const float4* bmr = (const float4*)(Bm + t*D_STATE + n0);
      float4 q0=bmr[0], q1=bmr[1];
      float bm[8] = {q0.x,q0.y,q0.z,q0.w, q1.x,q1.y,q1.z,q1.w};
      float dx = dl * xv;
      float y = 0.f;
      #pragma unroll
      for (int j=0;j<8;j++){
        s[j] = fmaf(__expf(dl * Aa[j]), s[j], dx * bm[j]);
        y = fmaf(s[j], bm[j], y);
      }
      float yo = half ? (y * zv) : ((y + Dv*xv) * zv);
      (half ? y1ls : y0ls)[l][d] = f2b(yo);
    }
  }
  __syncthreads();
  // ---- out-proj GEMM: 8 waves, wave w -> cols w*16..+15; K=256 over both y-halves ----
  int lane = tid & 63, w = tid >> 6;
  int fr = lane & 15, fq = lane >> 4;
  f32x4 acc[2] = {};
  #pragma unroll
  for (int kf=0; kf<8; kf++){
    bf16x8 bfrag = *(const bf16x8*)(wout + (size_t)(w*16+fr)*D_INNER + kf*32 + fq*8);
    bf16x8 a0 = *(bf16x8*)&y0ls[fr][kf*32 + fq*8];
    bf16x8 a1 = *(bf16x8*)&y0ls[16+fr][kf*32 + fq*8];
    bf16x8 c0 = *(bf16x8*)&y1ls[fr][kf*32 + fq*8];
    bf16x8 c1 = *(bf16x8*)&y1ls[16+fr][kf*32 + fq*8];
    acc[0] = __builtin_amdgcn_mfma_f32_16x16x32_bf16(a0, bfrag, acc[0], 0,0,0);
    acc[1] = __builtin_amdgcn_mfma_f32_16x16x32_bf16(a1, bfrag, acc[1], 0,0,0);
    acc[0] = __builtin_amdgcn_mfma_f32_16x16x32_bf16(c0, bfrag, acc[0], 0,0,0);
    acc[1] = __builtin_amdgcn_mfma_f32_16x16x32_bf16(c1, bfrag, acc[1], 0,0,0);
  }
  __syncthreads();
  // ---- residual add into LDS fp32 (alias y0ls) ----
  float* hls = (float*)&y0ls[0][0];     // [32][132]
  #pragma unroll
  for (int mt=0;mt<2;mt++)
    #pragma unroll
    for (int q=0;q<4;q++){
      int grow = mt*16 + fq*4 + q;
      int gcol = w*16 + fr;
      size_t gidx = (t0 + grow)*D_MODEL + gcol;
      float v = acc[mt][q] + h[gidx];
      if (MODE == 0) h[gidx] = v;
      hls[grow*132 + gcol] = v;
    }
  __syncthreads();
  // ---- LN over 32 rows ----
  int row = tid & 31, grp = tid >> 5;   // 16 groups x 8 cols
  float ps=0.f, pq=0.f;
  #pragma unroll
  for (int j=0;j<8;j++){ float xv = hls[row*132 + grp*8 + j]; ps += xv; pq += xv*xv; }
  psum[grp][row]=ps; psumsq[grp][row]=pq;
  __syncthreads();
  if (tid < 32){
    float S=0.f, Q=0.f;
    #pragma unroll
    for (int g=0;g<16;g++){ S+=psum[g][tid]; Q+=psumsq[g][tid]; }
    float mu = S*(1.f/128.f);
    mu_s[tid]=mu; rs_s[tid]=rsqrtf(Q*(1.f/128.f)-mu*mu+LN_EPS);
  }
  __syncthreads();
  #pragma unroll
  for (int j=0;j<8;j++){
    int c = grp*8 + j;
    float o = (hls[row*132+c]-mu_s[row])*rs_s[row]*lnw[c]+lnb[c];
    if (MODE == 0) hnbf[(t0+row)*D_MODEL + c] = __float2bfloat16(o);
    else           h[(t0+row)*D_MODEL + c] = o;
  }
}

extern "C" void kernel_launch(void* const* d_in, const int* in_sizes, int n_in,
                              void* d_out, int out_size, void* d_ws, size_t ws_size,
                              hipStream_t stream){
  const float* x      = (const float*)d_in[0];
  const float* inp_w  = (const float*)d_in[1];
  const float* inp_b  = (const float*)d_in[2];
  const float* ln_w   = (const float*)d_in[3];
  const float* ln_b   = (const float*)d_in[4];
  const float* in_w   = (const float*)d_in[5];
  const float* conv_w = (const float*)d_in[6];
  const float* conv_b = (const float*)d_in[7];
  const float* xproj_w= (const float*)d_in[8];
  const float* dt_w   = (const float*)d_in[9];
  const float* dt_b   = (const float*)d_in[10];
  const float* A_log  = (const float*)d_in[11];
  const float* Dp     = (const float*)d_in[12];
  const float* out_w  = (const float*)d_in[13];
  const float* fn_w   = (const float*)d_in[14];
  const float* fn_b   = (const float*)d_in[15];

  float* h = (float*)d_out;                           // (NTOK,128) residual stream

  __hip_bfloat16* zs   = (__hip_bfloat16*)d_ws;       // NTOK*256 (silu(z))
  __hip_bfloat16* xi   = zs   + (size_t)NTOK*256;     // NTOK*256
  __hip_bfloat16* dlt  = xi   + (size_t)NTOK*256;     // NTOK*256
  __hip_bfloat16* hnbf = dlt  + (size_t)NTOK*256;     // NTOK*128
  float* Bm    = (float*)(hnbf + (size_t)NTOK*128);   // NTOK*16
  float* cs    = Bm + (size_t)NTOK*16;                // 512*256*16
  float* sumdlt= cs + (size_t)BATCH*NC*D_INNER*D_STATE;
  __hip_bfloat16* w_inpT = (__hip_bfloat16*)(sumdlt + (size_t)BATCH*NC*D_INNER);
  __hip_bfloat16* w_inT  = w_inpT + 128*64;           // 2 * 512*128
  __hip_bfloat16* w_bdT  = w_inT  + 2*512*128;        // 2 * 272*256
  __hip_bfloat16* w_outT = w_bdT  + 2*272*256;        // 2 * 128*256

  CT ct;
  ct.src[0]=inp_w;        ct.dst[0]=w_inpT;              ct.lg2K[0]=6; ct.ld[0]=128; ct.coff[0]=0;
  ct.src[1]=in_w;         ct.dst[1]=w_inT;               ct.lg2K[1]=7; ct.ld[1]=512; ct.coff[1]=0;
  ct.src[2]=in_w+65536;   ct.dst[2]=w_inT+65536;         ct.lg2K[2]=7; ct.ld[2]=512; ct.coff[2]=0;
  ct.src[3]=dt_w;         ct.dst[3]=w_bdT;               ct.lg2K[3]=8; ct.ld[3]=256; ct.coff[3]=0;
  ct.src[4]=dt_w+65536;   ct.dst[4]=w_bdT+272*256;       ct.lg2K[4]=8; ct.ld[4]=256; ct.coff[4]=0;
  ct.src[5]=xproj_w;      ct.dst[5]=w_bdT+256*256;       ct.lg2K[5]=8; ct.ld[5]=32;  ct.coff[5]=16;
  ct.src[6]=xproj_w+8192; ct.dst[6]=w_bdT+272*256+256*256; ct.lg2K[6]=8; ct.ld[6]=32; ct.coff[6]=16;
  ct.src[7]=out_w;        ct.dst[7]=w_outT;              ct.lg2K[7]=8; ct.ld[7]=128; ct.coff[7]=0;
  ct.src[8]=out_w+32768;  ct.dst[8]=w_outT+32768;        ct.lg2K[8]=8; ct.ld[8]=128; ct.coff[8]=0;
  int bs[9] = {0,32,288,544,800,1056,1072,1088,1216};
  for (int i=0;i<9;i++) ct.bstart[i]=bs[i];
  convT_all<<<1344, 256, 0, stream>>>(ct);

  inp_ln_kernel<<<NTOK/64, 256, 0, stream>>>(x, w_inpT, inp_b, h, hnbf, ln_w, ln_b);

  for (int i=0;i<N_LAYERS;i++){
    const float* Al = A_log + (size_t)i*D_INNER*D_STATE;
    mega32<<<BATCH*NC, 512, 0, stream>>>(
        hnbf, w_inT + (size_t)i*512*128, w_bdT + (size_t)i*272*256,
        conv_w + i*D_INNER*D_CONVK, conv_b + i*D_INNER,
        dt_b + i*D_INNER, Al,
        zs, xi, dlt, Bm, cs, sumdlt);
    scan_p2<<<256, 256, 0, stream>>>(Al, cs, sumdlt);
    if (i == 0)
      scan_out_kernel<0><<<BATCH*NC, 512, 0, stream>>>(
          dlt, xi, Bm, zs, Al, Dp + i*D_INNER, cs, w_outT + (size_t)i*128*256,
          h, hnbf, ln_w + D_MODEL, ln_b + D_MODEL);
    else
      scan_out_kernel<1><<<BATCH*NC, 512, 0, stream>>>(
          dlt, xi, Bm, zs, Al, Dp + i*D_INNER, cs, w_outT + (size_t)i*128*256,
          h, nullptr, fn_w, fn_b);
  }
}

// Round 8
// 208.339 us; speedup vs baseline: 1.7080x; 1.0283x over previous
//
#include <hip/hip_runtime.h>
#include <hip/hip_bf16.h>
#include <cstddef>

#define BATCH   16
#define SEQ     1024
#define D_MODEL 128
#define D_STATE 16
#define D_CONVK 4
#define D_INNER 256
#define N_LAYERS 2
#define NTOK    (BATCH*SEQ)   /* 16384 */
#define LN_EPS  1e-5f
#define CL      32            /* scan chunk length */
#define NC      32            /* chunks per sequence */

typedef __attribute__((ext_vector_type(8))) short bf16x8;
typedef __attribute__((ext_vector_type(4))) float f32x4;

__device__ __forceinline__ float siluf(float v){ return v / (1.f + __expf(-v)); }
__device__ __forceinline__ float softplusf(float x){ return x > 20.f ? x : log1pf(__expf(x)); }
__device__ __forceinline__ short f2b(float f){
  __hip_bfloat16 h = __float2bfloat16(f);
  return *reinterpret_cast<short*>(&h);
}
__device__ __forceinline__ float b2f(short s){
  union { unsigned u; float f; } v; v.u = ((unsigned)(unsigned short)s) << 16; return v.f;
}

// ---------------- fused weight transpose+convert (all weights, one kernel) ----------------
struct CT {
  const float* src[9];
  __hip_bfloat16* dst[9];
  int lg2K[9], ld[9], coff[9];
  int bstart[9];
};
__global__ __launch_bounds__(256) void convT_all(CT c){
  int bid = blockIdx.x, r = 0;
  #pragma unroll
  for (int i=1;i<9;i++) r = (bid >= c.bstart[i]) ? i : r;
  int idx = (bid - c.bstart[r])*256 + threadIdx.x;
  int lg = c.lg2K[r];
  int k = idx & ((1<<lg)-1), n = idx >> lg;
  c.dst[r][idx] = __float2bfloat16(c.src[r][(size_t)k*c.ld[r] + c.coff[r] + n]);
}

// ---------------- fused input-proj GEMM + LN0 ----------------
__global__ __launch_bounds__(256) void inp_ln_kernel(
    const float* __restrict__ x, const __hip_bfloat16* __restrict__ wb,
    const float* __restrict__ bias, float* __restrict__ h,
    __hip_bfloat16* __restrict__ hnbf,
    const float* __restrict__ lnw, const float* __restrict__ lnb){
  __shared__ __align__(16) short As[64][72];
  __shared__ __align__(16) short Bs[128][72];
  __shared__ float hls[64][133];
  __shared__ float psum[4][64], psumsq[4][64], mu_s[64], rs_s[64];
  int tid = threadIdx.x;
  int row0 = blockIdx.x*64;
  int r = tid>>2, seg = tid&3;
  #pragma unroll
  for (int k0=0;k0<64;k0+=32){
    const float* Af = x + (size_t)(row0+r)*64 + k0 + seg*8;
    float4 a0 = *(const float4*)Af;
    float4 a1 = *(const float4*)(Af+4);
    bf16x8 v;
    v[0]=f2b(a0.x); v[1]=f2b(a0.y); v[2]=f2b(a0.z); v[3]=f2b(a0.w);
    v[4]=f2b(a1.x); v[5]=f2b(a1.y); v[6]=f2b(a1.z); v[7]=f2b(a1.w);
    *(bf16x8*)&As[r][k0+seg*8] = v;
  }
  {
    int br = tid>>1, half = tid&1;
    #pragma unroll
    for (int j=0;j<4;j++)
      *(bf16x8*)&Bs[br][half*32+j*8] = *(const bf16x8*)(wb + (size_t)br*64 + half*32 + j*8);
  }
  __syncthreads();
  int lane = tid&63, w = tid>>6;
  int wr = (w>>1)*32, wc = (w&1)*64;
  int fr = lane&15, fq = lane>>4;
  f32x4 acc[2][4] = {};
  #pragma unroll
  for (int k0=0;k0<64;k0+=32){
    bf16x8 a0 = *(bf16x8*)&As[wr+fr][k0+fq*8];
    bf16x8 a1 = *(bf16x8*)&As[wr+16+fr][k0+fq*8];
    #pragma unroll
    for (int nf=0;nf<4;nf++){
      bf16x8 bb = *(bf16x8*)&Bs[wc+nf*16+fr][k0+fq*8];
      acc[0][nf] = __builtin_amdgcn_mfma_f32_16x16x32_bf16(a0, bb, acc[0][nf], 0,0,0);
      acc[1][nf] = __builtin_amdgcn_mfma_f32_16x16x32_bf16(a1, bb, acc[1][nf], 0,0,0);
    }
  }
  #pragma unroll
  for (int mf=0;mf<2;mf++)
    #pragma unroll
    for (int nf=0;nf<4;nf++)
      #pragma unroll
      for (int q=0;q<4;q++){
        int grow = wr + mf*16 + fq*4 + q;
        int gcol = wc + nf*16 + fr;
        float v = acc[mf][nf][q] + bias[gcol];
        h[(size_t)(row0+grow)*D_MODEL + gcol] = v;
        hls[grow][gcol] = v;
      }
  __syncthreads();
  int row = tid&63, grp = tid>>6;
  float ps=0.f, pq=0.f;
  #pragma unroll
  for (int j=0;j<32;j++){ float xv = hls[row][grp*32+j]; ps += xv; pq += xv*xv; }
  psum[grp][row]=ps; psumsq[grp][row]=pq;
  __syncthreads();
  if (tid < 64){
    float S=0.f, Q=0.f;
    #pragma unroll
    for (int g=0;g<4;g++){ S+=psum[g][tid]; Q+=psumsq[g][tid]; }
    float mu = S*(1.f/128.f);
    mu_s[tid]=mu; rs_s[tid]=rsqrtf(Q*(1.f/128.f)-mu*mu+LN_EPS);
  }
  __syncthreads();
  #pragma unroll
  for (int j=0;j<32;j++){
    int c = grp*32+j;
    float o = (hls[row][c]-mu_s[row])*rs_s[row]*lnw[c]+lnb[c];
    hnbf[(size_t)(row0+row)*D_MODEL + c] = __float2bfloat16(o);
  }
}

// ---------------- MEGA kernel (32-token tile): in-proj + conv + silu + dt/Bm + local scan ----------------
// grid = BATCH*NC = 512 blocks, 512 threads = 8 waves
__global__ __launch_bounds__(512,4) void mega32(
    const __hip_bfloat16* __restrict__ hnbf,
    const __hip_bfloat16* __restrict__ w_in,   // [512][128]
    const __hip_bfloat16* __restrict__ w_bd,   // [272][256]
    const float* __restrict__ cw, const float* __restrict__ cb,
    const float* __restrict__ dt_b, const float* __restrict__ A_log,
    __hip_bfloat16* __restrict__ zs, __hip_bfloat16* __restrict__ xi,
    __hip_bfloat16* __restrict__ dltg, float* __restrict__ Bmg,
    float* __restrict__ cs, float* __restrict__ sumdlt){
  __shared__ __align__(16) short hn_s[48][136];     // rows t0-3..t0+31 real (0..34), 35..47 zero
  __shared__ __align__(16) short xraw_s[35][264];   // later aliased by dlt
  __shared__ __align__(16) short xi_s[32][264];
  __shared__ __align__(16) float Bm_s[32][16];
  short* dlt_s = &xraw_s[0][0];                     // [32][264] after conv done

  int tid = threadIdx.x;
  int blk = blockIdx.x;                 // b*NC + seg
  int seg = blk & 31;
  int b = blk >> 5;
  size_t t0 = (size_t)b*SEQ + (size_t)seg*CL;

  int w = tid >> 6, lane = tid & 63;
  int fr = lane & 15, fq = lane >> 4;

  // ---- stage hn rows into LDS (zero-padded halo + tail) ----
  for (int idx = tid; idx < 48*16; idx += 512){
    int r = idx >> 4, c8 = (idx & 15) * 8;
    bf16x8 v = {0,0,0,0,0,0,0,0};
    if (r < 35 && !(seg == 0 && r < 3))
      v = *(const bf16x8*)(hnbf + (t0 - 3 + r)*D_MODEL + c8);
    *(bf16x8*)&hn_s[r][c8] = v;
  }
  __syncthreads();

  // ---- GEMM1: A-frags hoisted from LDS once; wave w -> cols w*64..w*64+63 of 512 ----
  {
    bf16x8 Af[3][4];
    #pragma unroll
    for (int mt=0;mt<3;mt++)
      #pragma unroll
      for (int kf=0;kf<4;kf++)
        Af[mt][kf] = *(bf16x8*)&hn_s[mt*16+fr][kf*32+fq*8];
    f32x4 acc1[3][4] = {};
    #pragma unroll
    for (int nf=0;nf<4;nf++){
      bf16x8 Bf[4];
      #pragma unroll
      for (int kf=0;kf<4;kf++)
        Bf[kf] = *(const bf16x8*)(w_in + (size_t)(w*64+nf*16+fr)*D_MODEL + kf*32 + fq*8);
      #pragma unroll
      for (int mt=0;mt<3;mt++)
        #pragma unroll
        for (int kf=0;kf<4;kf++)
          acc1[mt][nf] = __builtin_amdgcn_mfma_f32_16x16x32_bf16(Af[mt][kf], Bf[kf], acc1[mt][nf], 0,0,0);
    }
    #pragma unroll
    for (int mt=0;mt<3;mt++)
      #pragma unroll
      for (int nf=0;nf<4;nf++)
        #pragma unroll
        for (int q=0;q<4;q++){
          int row = mt*16 + fq*4 + q;       // 0..47, valid 0..34
          int col = w*64 + nf*16 + fr;
          float v = acc1[mt][nf][q];
          if (row < 35){
            if (col < D_INNER){
              xraw_s[row][col] = f2b(v);    // seg==0 halo rows auto-zero via staged zeros
            } else if (row >= 3){
              zs[(t0 + row - 3)*D_INNER + (col - D_INNER)] = __float2bfloat16(siluf(v));
            }
          }
        }
  }
  __syncthreads();

  // ---- conv(K=4) + bias + silu -> xi_s + xi global ----
  #pragma unroll
  for (int rep=0;rep<2;rep++){
    int item = rep*512 + tid;             // 1024 = 32 tok x 32 dgroups
    int tok = item >> 5, d0 = (item & 31) << 3;
    float acc[8];
    #pragma unroll
    for (int j=0;j<8;j++) acc[j] = cb[d0+j];
    #pragma unroll
    for (int k=0;k<D_CONVK;k++){
      bf16x8 v = *(bf16x8*)&xraw_s[tok + k][d0];
      #pragma unroll
      for (int j=0;j<8;j++)
        acc[j] = fmaf(b2f(v[j]), cw[(d0+j)*D_CONVK + k], acc[j]);
    }
    bf16x8 o;
    #pragma unroll
    for (int j=0;j<8;j++) o[j] = f2b(siluf(acc[j]));
    *(bf16x8*)&xi_s[tok][d0] = o;
    *(bf16x8*)(xi + (t0+tok)*D_INNER + d0) = o;
  }
  __syncthreads();

  // ---- GEMM2: dlt(softplus)|Bm = xi_s[32x256] @ w_bd[272x256]^T ----
  {
    int nfc = (w==7) ? 3 : 2;
    f32x4 acc2[3][2] = {};
    bf16x8 A2[8][2];
    #pragma unroll
    for (int kf=0;kf<8;kf++)
      #pragma unroll
      for (int mt=0;mt<2;mt++)
        A2[kf][mt] = *(bf16x8*)&xi_s[mt*16+fr][kf*32 + fq*8];
    #pragma unroll
    for (int nfi=0;nfi<3;nfi++){
      if (nfi < nfc){
        int nfrag = (nfi==2) ? 16 : 2*w + nfi;
        #pragma unroll
        for (int kf=0;kf<8;kf++){
          bf16x8 Bv = *(const bf16x8*)(w_bd + (size_t)(nfrag*16+fr)*256 + kf*32 + fq*8);
          #pragma unroll
          for (int mt=0;mt<2;mt++)
            acc2[nfi][mt] = __builtin_amdgcn_mfma_f32_16x16x32_bf16(A2[kf][mt], Bv, acc2[nfi][mt], 0,0,0);
        }
      }
    }
    #pragma unroll
    for (int nfi=0;nfi<3;nfi++){
      if (nfi < nfc){
        int nfrag = (nfi==2) ? 16 : 2*w + nfi;
        #pragma unroll
        for (int mt=0;mt<2;mt++)
          #pragma unroll
          for (int q=0;q<4;q++){
            int row = mt*16 + fq*4 + q;
            float v = acc2[nfi][mt][q];
            if (nfrag < 16){
              int col = nfrag*16 + fr;
              float sp = softplusf(v + dt_b[col]);
              dlt_s[row*264 + col] = f2b(sp);
              dltg[(t0+row)*D_INNER + col] = __float2bfloat16(sp);
            } else {
              Bm_s[row][fr] = v;
              Bmg[(t0+row)*D_STATE + fr] = v;
            }
          }
      }
    }
  }
  __syncthreads();

  // ---- local scan (p1): 1 chunk, 2 threads/channel (8 states each), all from LDS ----
  {
    int d = tid & 255, half = tid >> 8, n0 = half*8;
    float Aa[8];
    #pragma unroll
    for (int j=0;j<8;j++) Aa[j] = -__expf(A_log[d*D_STATE + n0 + j]);
    float s[8] = {};
    float sd = 0.f;
    #pragma unroll 4
    for (int l=0; l<CL; l++){
      float dl = b2f(dlt_s[l*264 + d]);
      float xv = b2f(xi_s[l][d]);
      const float4* bp = (const float4*)&Bm_s[l][n0];
      float4 b0 = bp[0], b1 = bp[1];
      float bm[8] = {b0.x,b0.y,b0.z,b0.w, b1.x,b1.y,b1.z,b1.w};
      sd += dl;
      float dx = dl * xv;
      #pragma unroll
      for (int j=0;j<8;j++)
        s[j] = fmaf(__expf(dl * Aa[j]), s[j], dx * bm[j]);
    }
    float4* outp = (float4*)(cs + ((size_t)blk*D_INNER + d)*D_STATE + n0);
    outp[0] = make_float4(s[0],s[1],s[2],s[3]);
    outp[1] = make_float4(s[4],s[5],s[6],s[7]);
    if (half == 0) sumdlt[(size_t)blk*D_INNER + d] = sd;
  }
}

// ---------------- chunk combine: one thread per (b,d,n) chain ----------------
__global__ __launch_bounds__(256) void scan_p2(
    const float* __restrict__ A_log, float* __restrict__ cs,
    const float* __restrict__ sumdlt){
  int b = blockIdx.x >> 4;
  int dhi = blockIdx.x & 15;
  int d = dhi*16 + (threadIdx.x >> 4);
  int n = threadIdx.x & 15;
  float Aa = -__expf(A_log[d*D_STATE + n]);
  float s = 0.f;
  for (int c=0;c<NC;c++){
    size_t bc = (size_t)b*NC + c;
    float se = cs[(bc*D_INNER + d)*D_STATE + n];
    float sd = sumdlt[bc*D_INNER + d];
    cs[(bc*D_INNER + d)*D_STATE + n] = s;
    s = fmaf(__expf(Aa*sd), s, se);
  }
}

// ---------------- Fused: scan phase-3 (state-halved) + out-proj GEMM + residual + LN ----------------
template<int MODE>
__global__ __launch_bounds__(512,4) void scan_out_kernel(
    const __hip_bfloat16* __restrict__ dlt, const __hip_bfloat16* __restrict__ xi,
    const float* __restrict__ Bm, const __hip_bfloat16* __restrict__ zs,
    const float* __restrict__ A_log, const float* __restrict__ Dp,
    const float* __restrict__ cs, const __hip_bfloat16* __restrict__ wout,
    float* __restrict__ h, __hip_bfloat16* __restrict__ hnbf,
    const float* __restrict__ lnw, const float* __restrict__ lnb){
  __shared__ __align__(16) short y0ls[32][264];   // aliased later as float hls[32][132]
  __shared__ __align__(16) short y1ls[32][264];
  __shared__ float psum[16][32], psumsq[16][32], mu_s[32], rs_s[32];
  int blk = blockIdx.x;                 // b*NC + ct
  int b = blk >> 5, ct = blk & 31;
  int tid = threadIdx.x;
  size_t t0 = (size_t)b*SEQ + (size_t)ct*CL;
  {
    int d = tid & 255, half = tid >> 8, n0 = half*8;
    float Aa[8];
    #pragma unroll
    for (int j=0;j<8;j++) Aa[j] = -__expf(A_log[d*D_STATE + n0 + j]);
    float Dv = Dp[d];
    const float4* sp = (const float4*)(cs + ((size_t)blk*D_INNER + d)*D_STATE + n0);
    float4 s0=sp[0], s1=sp[1];
    float s[8] = {s0.x,s0.y,s0.z,s0.w, s1.x,s1.y,s1.z,s1.w};
    #pragma unroll 4
    for (int l=0; l<CL; l++){
      size_t t = t0 + l;
      float dl = __bfloat162float(dlt[t*D_INNER + d]);
      float xv = __bfloat162float(xi[t*D_INNER + d]);
      float zv = __bfloat162float(zs[t*D_INNER + d]);
      const float4* bmr = (const float4*)(Bm + t*D_STATE + n0);
      float4 q0=bmr[0], q1=bmr[1];
      float bm[8] = {q0.x,q0.y,q0.z,q0.w, q1.x,q1.y,q1.z,q1.w};
      float dx = dl * xv;
      float y = 0.f;
      #pragma unroll
      for (int j=0;j<8;j++){
        s[j] = fmaf(__expf(dl * Aa[j]), s[j], dx * bm[j]);
        y = fmaf(s[j], bm[j], y);
      }
      float yo = half ? (y * zv) : ((y + Dv*xv) * zv);
      (half ? y1ls : y0ls)[l][d] = f2b(yo);
    }
  }
  __syncthreads();
  int lane = tid & 63, w = tid >> 6;
  int fr = lane & 15, fq = lane >> 4;
  f32x4 acc[2] = {};
  #pragma unroll
  for (int kf=0; kf<8; kf++){
    bf16x8 bfrag = *(const bf16x8*)(wout + (size_t)(w*16+fr)*D_INNER + kf*32 + fq*8);
    bf16x8 a0 = *(bf16x8*)&y0ls[fr][kf*32 + fq*8];
    bf16x8 a1 = *(bf16x8*)&y0ls[16+fr][kf*32 + fq*8];
    bf16x8 c0 = *(bf16x8*)&y1ls[fr][kf*32 + fq*8];
    bf16x8 c1 = *(bf16x8*)&y1ls[16+fr][kf*32 + fq*8];
    acc[0] = __builtin_amdgcn_mfma_f32_16x16x32_bf16(a0, bfrag, acc[0], 0,0,0);
    acc[1] = __builtin_amdgcn_mfma_f32_16x16x32_bf16(a1, bfrag, acc[1], 0,0,0);
    acc[0] = __builtin_amdgcn_mfma_f32_16x16x32_bf16(c0, bfrag, acc[0], 0,0,0);
    acc[1] = __builtin_amdgcn_mfma_f32_16x16x32_bf16(c1, bfrag, acc[1], 0,0,0);
  }
  __syncthreads();
  float* hls = (float*)&y0ls[0][0];     // [32][132]
  #pragma unroll
  for (int mt=0;mt<2;mt++)
    #pragma unroll
    for (int q=0;q<4;q++){
      int grow = mt*16 + fq*4 + q;
      int gcol = w*16 + fr;
      size_t gidx = (t0 + grow)*D_MODEL + gcol;
      float v = acc[mt][q] + h[gidx];
      if (MODE == 0) h[gidx] = v;
      hls[grow*132 + gcol] = v;
    }
  __syncthreads();
  int row = tid & 31, grp = tid >> 5;
  float ps=0.f, pq=0.f;
  #pragma unroll
  for (int j=0;j<8;j++){ float xv = hls[row*132 + grp*8 + j]; ps += xv; pq += xv*xv; }
  psum[grp][row]=ps; psumsq[grp][row]=pq;
  __syncthreads();
  if (tid < 32){
    float S=0.f, Q=0.f;
    #pragma unroll
    for (int g=0;g<16;g++){ S+=psum[g][tid]; Q+=psumsq[g][tid]; }
    float mu = S*(1.f/128.f);
    mu_s[tid]=mu; rs_s[tid]=rsqrtf(Q*(1.f/128.f)-mu*mu+LN_EPS);
  }
  __syncthreads();
  #pragma unroll
  for (int j=0;j<8;j++){
    int c = grp*8 + j;
    float o = (hls[row*132+c]-mu_s[row])*rs_s[row]*lnw[c]+lnb[c];
    if (MODE == 0) hnbf[(t0+row)*D_MODEL + c] = __float2bfloat16(o);
    else           h[(t0+row)*D_MODEL + c] = o;
  }
}

extern "C" void kernel_launch(void* const* d_in, const int* in_sizes, int n_in,
                              void* d_out, int out_size, void* d_ws, size_t ws_size,
                              hipStream_t stream){
  const float* x      = (const float*)d_in[0];
  const float* inp_w  = (const float*)d_in[1];
  const float* inp_b  = (const float*)d_in[2];
  const float* ln_w   = (const float*)d_in[3];
  const float* ln_b   = (const float*)d_in[4];
  const float* in_w   = (const float*)d_in[5];
  const float* conv_w = (const float*)d_in[6];
  const float* conv_b = (const float*)d_in[7];
  const float* xproj_w= (const float*)d_in[8];
  const float* dt_w   = (const float*)d_in[9];
  const float* dt_b   = (const float*)d_in[10];
  const float* A_log  = (const float*)d_in[11];
  const float* Dp     = (const float*)d_in[12];
  const float* out_w  = (const float*)d_in[13];
  const float* fn_w   = (const float*)d_in[14];
  const float* fn_b   = (const float*)d_in[15];

  float* h = (float*)d_out;                           // (NTOK,128) residual stream

  __hip_bfloat16* zs   = (__hip_bfloat16*)d_ws;       // NTOK*256 (silu(z))
  __hip_bfloat16* xi   = zs   + (size_t)NTOK*256;     // NTOK*256
  __hip_bfloat16* dlt  = xi   + (size_t)NTOK*256;     // NTOK*256
  __hip_bfloat16* hnbf = dlt  + (size_t)NTOK*256;     // NTOK*128
  float* Bm    = (float*)(hnbf + (size_t)NTOK*128);   // NTOK*16
  float* cs    = Bm + (size_t)NTOK*16;                // 512*256*16
  float* sumdlt= cs + (size_t)BATCH*NC*D_INNER*D_STATE;
  __hip_bfloat16* w_inpT = (__hip_bfloat16*)(sumdlt + (size_t)BATCH*NC*D_INNER);
  __hip_bfloat16* w_inT  = w_inpT + 128*64;           // 2 * 512*128
  __hip_bfloat16* w_bdT  = w_inT  + 2*512*128;        // 2 * 272*256
  __hip_bfloat16* w_outT = w_bdT  + 2*272*256;        // 2 * 128*256

  CT ct;
  ct.src[0]=inp_w;        ct.dst[0]=w_inpT;              ct.lg2K[0]=6; ct.ld[0]=128; ct.coff[0]=0;
  ct.src[1]=in_w;         ct.dst[1]=w_inT;               ct.lg2K[1]=7; ct.ld[1]=512; ct.coff[1]=0;
  ct.src[2]=in_w+65536;   ct.dst[2]=w_inT+65536;         ct.lg2K[2]=7; ct.ld[2]=512; ct.coff[2]=0;
  ct.src[3]=dt_w;         ct.dst[3]=w_bdT;               ct.lg2K[3]=8; ct.ld[3]=256; ct.coff[3]=0;
  ct.src[4]=dt_w+65536;   ct.dst[4]=w_bdT+272*256;       ct.lg2K[4]=8; ct.ld[4]=256; ct.coff[4]=0;
  ct.src[5]=xproj_w;      ct.dst[5]=w_bdT+256*256;       ct.lg2K[5]=8; ct.ld[5]=32;  ct.coff[5]=16;
  ct.src[6]=xproj_w+8192; ct.dst[6]=w_bdT+272*256+256*256; ct.lg2K[6]=8; ct.ld[6]=32; ct.coff[6]=16;
  ct.src[7]=out_w;        ct.dst[7]=w_outT;              ct.lg2K[7]=8; ct.ld[7]=128; ct.coff[7]=0;
  ct.src[8]=out_w+32768;  ct.dst[8]=w_outT+32768;        ct.lg2K[8]=8; ct.ld[8]=128; ct.coff[8]=0;
  int bs[9] = {0,32,288,544,800,1056,1072,1088,1216};
  for (int i=0;i<9;i++) ct.bstart[i]=bs[i];
  convT_all<<<1344, 256, 0, stream>>>(ct);

  inp_ln_kernel<<<NTOK/64, 256, 0, stream>>>(x, w_inpT, inp_b, h, hnbf, ln_w, ln_b);

  for (int i=0;i<N_LAYERS;i++){
    const float* Al = A_log + (size_t)i*D_INNER*D_STATE;
    mega32<<<BATCH*NC, 512, 0, stream>>>(
        hnbf, w_inT + (size_t)i*512*128, w_bdT + (size_t)i*272*256,
        conv_w + i*D_INNER*D_CONVK, conv_b + i*D_INNER,
        dt_b + i*D_INNER, Al,
        zs, xi, dlt, Bm, cs, sumdlt);
    scan_p2<<<256, 256, 0, stream>>>(Al, cs, sumdlt);
    if (i == 0)
      scan_out_kernel<0><<<BATCH*NC, 512, 0, stream>>>(
          dlt, xi, Bm, zs, Al, Dp + i*D_INNER, cs, w_outT + (size_t)i*128*256,
          h, hnbf, ln_w + D_MODEL, ln_b + D_MODEL);
    else
      scan_out_kernel<1><<<BATCH*NC, 512, 0, stream>>>(
          dlt, xi, Bm, zs, Al, Dp + i*D_INNER, cs, w_outT + (size_t)i*128*256,
          h, nullptr, fn_w, fn_b);
  }
}